// Round 15
// baseline (3331.385 us; speedup 1.0000x reference)
//
#include <hip/hip_runtime.h>
#include <hip/hip_cooperative_groups.h>

namespace cg = cooperative_groups;

#define NB 32
#define TT 12
#define NN 512
#define HH 64
#define EE 10
#define XS 80       // X row width (halves)
#define KD 240      // dense K = 3*80
#define RS (NB*NN)  // 16384 global rows
#define TTNN (TT*NN)
#define GP 164

typedef _Float16 f16;
typedef __attribute__((ext_vector_type(4))) _Float16 f16x4;
typedef __attribute__((ext_vector_type(8))) _Float16 f16x8;
typedef __attribute__((ext_vector_type(4))) float f32x4;

#define MFMA32(a,bb,c) __builtin_amdgcn_mfma_f32_16x16x32_f16(a,bb,c,0,0,0)
#define MFMA16(a,bb,c) __builtin_amdgcn_mfma_f32_16x16x16f16(a,bb,c,0,0,0)

__device__ __forceinline__ void barrier_lgkm() {
  asm volatile("s_waitcnt lgkmcnt(0)" ::: "memory");
  __builtin_amdgcn_s_barrier();
  __builtin_amdgcn_sched_barrier(0);
}

union SMem {
  struct {
    f16 PsH[2][2][64][32], PsL[2][2][64][32];  // [buf][A=0/A2=1][row][k]
    f16 XtH[2][80][40], XtL[2][80][40];        // [buf][col][k]
  } s1;
  struct {
    f16 gH[64][GP], gL[64][GP];                // [row][g1|g2]
  } s2;
};

struct GruP {
  const f16 *AH, *AL, *A2H, *A2L; long long astr;
  f16 *XaRH,*XaRL,*XaCH,*XaCL, *XbRH,*XbRL,*XbCH,*XbCL;
  const f16 *WgH,*WgL,*WuH,*WuL;
  const float *gb,*ub;
  float *h,*rb;
  const float *x,*ycov,*pW,*pb;
  float *out;
};

// ---------------- fold Chebyshev into weights; transpose to [O][KD]; f16 split ----
__global__ void fold_w_t(const float* __restrict__ src, f16* __restrict__ WtH,
                         f16* __restrict__ WtL, int C, int O){
  int idx = blockIdx.x*256 + threadIdx.x;
  if (idx >= O*KD) return;
  int o = idx / KD;
  int k = idx % KD;
  int s = k / XS, c = k % XS;
  float v = 0.f;
  if (c < C) {
    if (s == 0)      v = src[c*O+o] - src[(2*C+c)*O+o];
    else if (s == 1) v = src[(C+c)*O+o];
    else             v = 2.f*src[(2*C+c)*O+o];
  }
  f16 hi = (f16)v;
  WtH[idx] = hi;
  WtL[idx] = (f16)(v - (float)hi);
}

// ---------------- A = softmax(relu(E E^T)): 8 rows/block, wave-per-row ----------
__global__ __launch_bounds__(512) void softmax_graph(
    const float* __restrict__ Emb, long long ebs,
    f16* __restrict__ AH, f16* __restrict__ AL, long long abs_)
{
  __shared__ float Es[NN*EE];
  int b  = blockIdx.x >> 6;
  int rt = blockIdx.x & 63;
  const float* Eb = Emb + (long long)b*ebs;
  int tid = threadIdx.x;
  for (int i = tid; i < NN*EE; i += 512) Es[i] = Eb[i];
  __syncthreads();
  int wave = tid >> 6, lane = tid & 63;
  int r = rt*8 + wave;
  float q[EE];
  #pragma unroll
  for (int e = 0; e < EE; ++e) q[e] = Es[r*EE + e];
  float sv[8];
  float mx = 0.f;
  #pragma unroll
  for (int j = 0; j < 8; ++j) {
    int m = 64*j + lane;
    float s = 0.f;
    #pragma unroll
    for (int e = 0; e < EE; ++e) s += q[e]*Es[m*EE + e];
    s = fmaxf(s, 0.f);
    sv[j] = s;
    mx = fmaxf(mx, s);
  }
  #pragma unroll
  for (int off = 32; off >= 1; off >>= 1) mx = fmaxf(mx, __shfl_xor(mx, off, 64));
  float sm = 0.f;
  #pragma unroll
  for (int j = 0; j < 8; ++j) { sv[j] = expf(sv[j] - mx); sm += sv[j]; }
  #pragma unroll
  for (int off = 32; off >= 1; off >>= 1) sm += __shfl_xor(sm, off, 64);
  float inv = 1.f / sm;
  #pragma unroll
  for (int j = 0; j < 8; ++j) {
    int m = 64*j + lane;
    float p = sv[j] * inv;
    long long o = (long long)b*abs_ + (long long)r*NN + m;
    f16 hi = (f16)p;
    AH[o] = hi;
    AL[o] = (f16)(p - (float)hi);
  }
}

// ---------------- B = A @ A (per batch), f16-split 3-product ---------------------
__global__ __launch_bounds__(256) void sq_mm(
    const f16* __restrict__ AH, const f16* __restrict__ AL, long long astr,
    f16* __restrict__ BH, f16* __restrict__ BL, long long bstr)
{
  __shared__ f16 RsH[64][36], RsL[64][36], CsH[64][34], CsL[64][34];
  int b = blockIdx.z;
  int rows0 = blockIdx.y*64, cols0 = blockIdx.x*64;
  const f16* Ah = AH + (long long)b*astr;
  const f16* Al = AL + (long long)b*astr;
  int tid = threadIdx.x, l = tid & 63, w = tid >> 6, lr = l & 15, lg = l >> 4;
  int ar = w*16 + lr;
  int st_row = tid >> 2, st_seg = tid & 3;
  int sx_m = tid >> 3, sx_sub = tid & 7;
  f32x4 acc[4] = {};
  for (int kt = 0; kt < 16; ++kt) {
    int k0 = kt*32;
    barrier_lgkm();
    {
      f16x8 vh = *(const f16x8*)&Ah[(long long)(rows0+st_row)*NN + k0 + 8*st_seg];
      f16x8 vl = *(const f16x8*)&Al[(long long)(rows0+st_row)*NN + k0 + 8*st_seg];
      *(f16x8*)&RsH[st_row][8*st_seg] = vh;
      *(f16x8*)&RsL[st_row][8*st_seg] = vl;
    }
    #pragma unroll
    for (int j = 0; j < 2; ++j) {
      int c4 = sx_sub + 8*j;   // 0..15
      f16x4 vh = *(const f16x4*)&Ah[(long long)(k0+sx_m)*NN + cols0 + 4*c4];
      f16x4 vl = *(const f16x4*)&Al[(long long)(k0+sx_m)*NN + cols0 + 4*c4];
      #pragma unroll
      for (int q = 0; q < 4; ++q) {
        CsH[4*c4+q][sx_m] = vh[q];
        CsL[4*c4+q][sx_m] = vl[q];
      }
    }
    barrier_lgkm();
    f16x8 a_h = *(const f16x8*)&RsH[ar][8*lg];
    f16x8 a_l = *(const f16x8*)&RsL[ar][8*lg];
    #pragma unroll
    for (int cf = 0; cf < 4; ++cf) {
      int c = cf*16 + lr;
      f16x8 b_h = *(const f16x8*)&CsH[c][8*lg];
      f16x8 b_l = *(const f16x8*)&CsL[c][8*lg];
      acc[cf] = MFMA32(a_h, b_h, acc[cf]);
      acc[cf] = MFMA32(a_h, b_l, acc[cf]);
      acc[cf] = MFMA32(a_l, b_h, acc[cf]);
    }
  }
  #pragma unroll
  for (int cf = 0; cf < 4; ++cf) {
    #pragma unroll
    for (int reg = 0; reg < 4; ++reg) {
      int r = rows0 + w*16 + lg*4 + reg;
      int c = cols0 + cf*16 + lr;
      float v = acc[cf][reg];
      f16 hi = (f16)v;
      long long o = (long long)b*bstr + (long long)r*NN + c;
      BH[o] = hi;
      BL[o] = (f16)(v - (float)hi);
    }
  }
}

// ---------------- write one special column of X (dual layout, split) -------------
__global__ void fill_col(f16* __restrict__ XRH, f16* __restrict__ XRL,
                         f16* __restrict__ XCH, f16* __restrict__ XCL, int col,
                         const float* __restrict__ src, long long sstr){
  int row = blockIdx.x*256 + threadIdx.x;
  if (row >= RS) return;
  float v = src[(long long)(row>>9)*sstr + (row & 511)];
  f16 hi = (f16)v;
  f16 lo = (f16)(v - (float)hi);
  XRH[(long long)row*XS + col] = hi;
  XRL[(long long)row*XS + col] = lo;
  XCH[(long long)col*RS + row] = hi;
  XCL[(long long)col*RS + row] = lo;
}

// ---------------- one GRU half-step phase (R13 fused_half body) ------------------
template<int GATE, int DEC>
__device__ __forceinline__ void do_phase(
    SMem& sm, float* gpart, const GruP& P,
    const f16* XiRH, const f16* XiRL, const f16* XiCH, const f16* XiCL,
    f16* XoRH, f16* XoRL, f16* XoCH, f16* XoCL,
    const f16* WH, const f16* WL, const float* bias,
    const float* s0src, const float* s1src,
    int t, int b, int rows0, int ns, int ns_next, int writeX)
{
  const long long bNN = (long long)b*NN;
  const int tid = threadIdx.x;
  const int w = tid >> 6, l = tid & 63;
  const int lr = l & 15, lg = l >> 4;
  const int grp = w >> 2;
  const int w4 = w & 3;
  const int ar = w4*16 + lr;
  const int asw = (ar >> 2) & 3;

  const int stw = (tid < 256) ? 0 : 1;
  const int at = tid & 255;
  const int st_row = at >> 2, st_seg = at & 3;
  const int a_sw = (st_row >> 2) & 3;
  const f16* PgH = (stw ? P.A2H : P.AH) + (long long)b*P.astr + (long long)rows0*NN;
  const f16* PgL = (stw ? P.A2L : P.AL) + (long long)b*P.astr + (long long)rows0*NN;

  const int xc = tid >> 3;
  const int xsub = tid & 7;
  const int xa = xsub >> 2;
  const int xo = xsub & 3;
  const int xc2 = (tid < 128) ? (64 + xc) : 64;
  const f16* XC1 = (xa ? XiCL : XiCH) + (long long)xc*RS + bNN;
  const f16* XC2 = (xa ? XiCL : XiCH) + (long long)xc2*RS + bNN;

  f16x8 rH0{}, rL0{}, x10{}, x20{}, rH1{}, rL1{}, x11{}, x21{};

  auto LOAD = [&](int kt, f16x8& rH, f16x8& rL, f16x8& x1, f16x8& x2){
    int k0 = kt*32;
    long long ao = (long long)st_row*NN + k0 + 8*st_seg;
    rH = *(const f16x8*)&PgH[ao];
    rL = *(const f16x8*)&PgL[ao];
    x1 = *(const f16x8*)&XC1[k0 + 8*xo];
    if (tid < 128) x2 = *(const f16x8*)&XC2[k0 + 8*xo];
  };
  auto STORE = [&](int buf, f16x8& rH, f16x8& rL, f16x8& x1, f16x8& x2){
    int sc = 8*(st_seg ^ a_sw);
    *(f16x8*)&sm.s1.PsH[buf][stw][st_row][sc] = rH;
    *(f16x8*)&sm.s1.PsL[buf][stw][st_row][sc] = rL;
    f16 (*xt)[40] = xa ? sm.s1.XtL[buf] : sm.s1.XtH[buf];
    *(f16x8*)&xt[xc][8*xo] = x1;
    if (tid < 128) *(f16x8*)&xt[64 + xc][8*xo] = x2;
  };
  f32x4 acc[5] = {};
  auto COMP = [&](int buf){
    int sa = 8*(lg ^ asw);
    f16x8 ah = *(const f16x8*)&sm.s1.PsH[buf][grp][ar][sa];
    f16x8 al2 = *(const f16x8*)&sm.s1.PsL[buf][grp][ar][sa];
    __builtin_amdgcn_s_setprio(1);
    #pragma unroll
    for (int cf = 0; cf < 5; ++cf) {
      int c = cf*16 + lr;
      f16x8 bh = *(const f16x8*)&sm.s1.XtH[buf][c][8*lg];
      f16x8 bl = *(const f16x8*)&sm.s1.XtL[buf][c][8*lg];
      acc[cf] = MFMA32(ah, bh, acc[cf]);
      acc[cf] = MFMA32(ah, bl, acc[cf]);
      acc[cf] = MFMA32(al2, bh, acc[cf]);
    }
    __builtin_amdgcn_s_setprio(0);
  };

  LOAD(0, rH0,rL0,x10,x20);
  LOAD(1, rH1,rL1,x11,x21);
  STORE(0, rH0,rL0,x10,x20);
  barrier_lgkm();
  #pragma unroll
  for (int kt2 = 0; kt2 < 8; ++kt2) {
    int kt = kt2*2;
    if (kt+2 < 16) LOAD(kt+2, rH0,rL0,x10,x20);
    COMP(0);
    STORE(1, rH1,rL1,x11,x21);
    barrier_lgkm();
    if (kt+3 < 16) LOAD(kt+3, rH1,rL1,x11,x21);
    COMP(1);
    if (kt+2 < 16) STORE(0, rH0,rL0,x10,x20);
    barrier_lgkm();
  }

  // ---- dump g (split) into LDS union (staging dead after final barrier) ----
  {
    int go_ = grp*80;
    #pragma unroll
    for (int cf = 0; cf < 5; ++cf) {
      int col = go_ + cf*16 + lr;
      #pragma unroll
      for (int reg = 0; reg < 4; ++reg) {
        int row = w4*16 + lg*4 + reg;
        float v = acc[cf][reg];
        f16 hi = (f16)v;
        sm.s2.gH[row][col] = hi;
        sm.s2.gL[row][col] = (f16)(v - (float)hi);
      }
    }
  }
  barrier_lgkm();

  // ---- dense: K = [x(rm global) | g1(LDS) | g2(LDS)], W from global ----
  constexpr int CFW = GATE ? 4 : 2;
  f32x4 accD[CFW] = {};
  const long long grow0 = bNN + rows0 + w4*16;
  const f16* xrH = XiRH + (grow0 + lr)*XS;
  const f16* xrL = XiRL + (grow0 + lr)*XS;
  #pragma unroll
  for (int c = 0; c < 15; ++c) {
    f16x4 a_h, a_l;
    if (c < 5) {
      a_h = *(const f16x4*)&xrH[c*16 + 4*lg];
      a_l = *(const f16x4*)&xrL[c*16 + 4*lg];
    } else {
      int gk = (c-5)*16 + 4*lg;
      a_h = *(const f16x4*)&sm.s2.gH[w4*16 + lr][gk];
      a_l = *(const f16x4*)&sm.s2.gL[w4*16 + lr][gk];
    }
    #pragma unroll
    for (int cf = 0; cf < CFW; ++cf) {
      int o = grp*(CFW*16) + cf*16 + lr;
      f16x4 b_h = *(const f16x4*)&WH[(long long)o*KD + c*16 + 4*lg];
      f16x4 b_l = *(const f16x4*)&WL[(long long)o*KD + c*16 + 4*lg];
      accD[cf] = MFMA16(a_h, b_h, accD[cf]);
      accD[cf] = MFMA16(a_h, b_l, accD[cf]);
      accD[cf] = MFMA16(a_l, b_h, accD[cf]);
    }
  }

  // ---- epilogue ----
  if constexpr (GATE) {
    #pragma unroll
    for (int cf = 0; cf < CFW; ++cf) {
      int o = grp*64 + cf*16 + lr;
      float bi = bias[o];
      #pragma unroll
      for (int reg = 0; reg < 4; ++reg) {
        long long grow = grow0 + lg*4 + reg;
        float v = 1.f/(1.f + expf(-(accD[cf][reg] + bi)));
        if (grp == 0) {
          float zh = v * P.h[grow*HH + o];
          f16 hi = (f16)zh; f16 lo = (f16)(zh - (float)hi);
          XoRH[grow*XS + ns + o] = hi; XoRL[grow*XS + ns + o] = lo;
          XoCH[(long long)(ns+o)*RS + grow] = hi; XoCL[(long long)(ns+o)*RS + grow] = lo;
        } else {
          P.rb[grow*HH + (o - HH)] = v;
        }
      }
    }
    if (grp == 0 && lr < ns) {
      #pragma unroll
      for (int reg = 0; reg < 4; ++reg) {
        long long grow = grow0 + lg*4 + reg;
        f16 vh = XiRH[grow*XS + lr], vl = XiRL[grow*XS + lr];
        XoRH[grow*XS + lr] = vh; XoRL[grow*XS + lr] = vl;
        XoCH[(long long)lr*RS + grow] = vh; XoCL[(long long)lr*RS + grow] = vl;
      }
    }
  } else {
    float gop[4] = {0.f,0.f,0.f,0.f};
    #pragma unroll
    for (int cf = 0; cf < CFW; ++cf) {
      int o = grp*32 + cf*16 + lr;
      float bi = bias[o];
      float pwv = 0.f;
      if constexpr (DEC) pwv = P.pW[o];
      #pragma unroll
      for (int reg = 0; reg < 4; ++reg) {
        long long grow = grow0 + lg*4 + reg;
        float hc = tanhf(accD[cf][reg] + bi);
        float rv = P.rb[grow*HH + o];
        float hv = P.h[grow*HH + o];
        float hn = rv*hv + (1.f - rv)*hc;
        P.h[grow*HH + o] = hn;
        if (writeX) {
          f16 hi = (f16)hn; f16 lo = (f16)(hn - (float)hi);
          XoRH[grow*XS + ns_next + o] = hi; XoRL[grow*XS + ns_next + o] = lo;
          XoCH[(long long)(ns_next+o)*RS + grow] = hi; XoCL[(long long)(ns_next+o)*RS + grow] = lo;
        }
        if constexpr (DEC) gop[reg] += hn * pwv;
      }
    }
    if constexpr (DEC) {
      #pragma unroll
      for (int reg = 0; reg < 4; ++reg) {
        #pragma unroll
        for (int off = 8; off >= 1; off >>= 1)
          gop[reg] += __shfl_xor(gop[reg], off, 64);
      }
      if (grp == 1 && lr == 0) {
        #pragma unroll
        for (int reg = 0; reg < 4; ++reg)
          gpart[w4*16 + lg*4 + reg] = gop[reg];
      }
      barrier_lgkm();
      if (grp == 0 && lr == 0) {
        float pb0 = P.pb[0];
        #pragma unroll
        for (int reg = 0; reg < 4; ++reg) {
          int n = rows0 + w4*16 + lg*4 + reg;
          long long grow = bNN + n;
          float go = gop[reg] + gpart[w4*16 + lg*4 + reg] + pb0;
          P.out[((long long)b*TT + t)*NN + n] = go;
          if (writeX) {
            f16 hi = (f16)go; f16 lo = (f16)(go - (float)hi);
            XoRH[grow*XS] = hi; XoRL[grow*XS] = lo;
            XoCH[grow] = hi; XoCL[grow] = lo;
            float yv = s1src[(long long)b*TTNN + n];
            f16 hy = (f16)yv; f16 ly = (f16)(yv - (float)hy);
            XoRH[grow*XS + 1] = hy; XoRL[grow*XS + 1] = ly;
            XoCH[RS + grow] = hy; XoCL[RS + grow] = ly;
          }
        }
      }
    } else {
      if (writeX && grp == 0 && lr == 0) {
        #pragma unroll
        for (int reg = 0; reg < 4; ++reg) {
          int n = rows0 + w4*16 + lg*4 + reg;
          long long grow = bNN + n;
          float v0 = s0src ? s0src[(long long)b*TTNN + n] : 0.f;
          f16 h0 = (f16)v0; f16 l0 = (f16)(v0 - (float)h0);
          XoRH[grow*XS] = h0; XoRL[grow*XS] = l0;
          XoCH[grow] = h0; XoCL[grow] = l0;
          if (ns_next == 2 && s1src) {
            float v1 = s1src[(long long)b*TTNN + n];
            f16 h1 = (f16)v1; f16 l1 = (f16)(v1 - (float)h1);
            XoRH[grow*XS + 1] = h1; XoRL[grow*XS + 1] = l1;
            XoCH[RS + grow] = h1; XoCL[RS + grow] = l1;
          }
        }
      }
    }
  }
}

// ---------------- persistent GRU sequence (cooperative, R13 body, no spill) ------
template<int DEC>
__global__ __launch_bounds__(512) void gru_seq(GruP P)
{
  cg::grid_group gridg = cg::this_grid();
  __shared__ SMem sm;
  __shared__ float gpart[64];
  const int b = blockIdx.x;
  const int rows0 = blockIdx.y * 64;
  const int ns = DEC ? 2 : 1;
  for (int t = 0; t < TT; ++t) {
    do_phase<1,DEC>(sm, gpart, P,
        P.XaRH,P.XaRL,P.XaCH,P.XaCL, P.XbRH,P.XbRL,P.XbCH,P.XbCL,
        P.WgH,P.WgL,P.gb, nullptr,nullptr,
        t, b, rows0, ns, 0, 1);
    gridg.sync();
    const float* s0p = nullptr;
    const float* s1p = nullptr;
    int nsn = ns, wX = 1;
    if (!DEC) {
      if (t < TT-1) { s0p = P.x + (size_t)(t+1)*NN; nsn = 1; }
      else          { s1p = P.ycov; nsn = 2; }   // s0p null -> v0 = 0
    } else {
      nsn = 2;
      if (t < TT-1) s1p = P.ycov + (size_t)(t+1)*NN;
      else          wX = 0;
    }
    do_phase<0,DEC>(sm, gpart, P,
        P.XbRH,P.XbRL,P.XbCH,P.XbCL, P.XaRH,P.XaRL,P.XaCH,P.XaCL,
        P.WuH,P.WuL,P.ub, s0p,s1p,
        t, b, rows0, ns, nsn, wX);
    if (t < TT-1) gridg.sync();
  }
}

// ---------------- E_dyn = ne + h @ hyper_W + hyper_b -----------------------------
__global__ __launch_bounds__(256) void edyn_k(
    const float* __restrict__ h, const float* __restrict__ ne,
    const float* __restrict__ hW, const float* __restrict__ hb, float* __restrict__ Ed)
{
  int row = blockIdx.x*4 + (threadIdx.x >> 6);
  int lane = threadIdx.x & 63;
  float hv = h[(long long)row*HH + lane];
  float myval = 0.f;
  #pragma unroll
  for (int e = 0; e < EE; ++e) {
    float v = hv * hW[lane*EE + e];
    #pragma unroll
    for (int off = 32; off >= 1; off >>= 1) v += __shfl_xor(v, off, 64);
    if (lane == e) myval = v;
  }
  if (lane < EE) {
    int n = row & 511;
    Ed[(long long)row*EE + lane] = ne[n*EE + lane] + hb[lane] + myval;
  }
}

extern "C" void kernel_launch(void* const* d_in, const int* in_sizes, int n_in,
                              void* d_out, int out_size, void* d_ws, size_t ws_size,
                              hipStream_t stream)
{
  const float* x    = (const float*)d_in[0];
  const float* ycov = (const float*)d_in[1];
  const float* ne   = (const float*)d_in[2];
  const float* egW  = (const float*)d_in[3];
  const float* egb  = (const float*)d_in[4];
  const float* euW  = (const float*)d_in[5];
  const float* eub  = (const float*)d_in[6];
  const float* dgW  = (const float*)d_in[7];
  const float* dgb  = (const float*)d_in[8];
  const float* duW  = (const float*)d_in[9];
  const float* dub  = (const float*)d_in[10];
  const float* pW   = (const float*)d_in[11];
  const float* pb   = (const float*)d_in[12];
  const float* hW   = (const float*)d_in[13];
  const float* hb   = (const float*)d_in[14];
  float* out = (float*)d_out;

  char* p = (char*)d_ws;
  f16* AsH  = (f16*)p; p += (size_t)NN*NN*2;
  f16* AsL  = (f16*)p; p += (size_t)NN*NN*2;
  f16* As2H = (f16*)p; p += (size_t)NN*NN*2;
  f16* As2L = (f16*)p; p += (size_t)NN*NN*2;
  f16* AdH  = (f16*)p; p += (size_t)NB*NN*NN*2;
  f16* AdL  = (f16*)p; p += (size_t)NB*NN*NN*2;
  f16* Ad2H = (f16*)p; p += (size_t)NB*NN*NN*2;
  f16* Ad2L = (f16*)p; p += (size_t)NB*NN*NN*2;
  f16* XaRH = (f16*)p; p += (size_t)RS*XS*2;
  f16* XaRL = (f16*)p; p += (size_t)RS*XS*2;
  f16* XaCH = (f16*)p; p += (size_t)RS*XS*2;
  f16* XaCL = (f16*)p; p += (size_t)RS*XS*2;
  f16* XbRH = (f16*)p; p += (size_t)RS*XS*2;
  f16* XbRL = (f16*)p; p += (size_t)RS*XS*2;
  f16* XbCH = (f16*)p; p += (size_t)RS*XS*2;
  f16* XbCL = (f16*)p; p += (size_t)RS*XS*2;
  float* h  = (float*)p; p += (size_t)RS*HH*4;
  float* rb = (float*)p; p += (size_t)RS*HH*4;
  float* Ed = (float*)p; p += (size_t)RS*EE*4;
  f16* WgeH = (f16*)p; p += (size_t)128*KD*2;
  f16* WgeL = (f16*)p; p += (size_t)128*KD*2;
  f16* WueH = (f16*)p; p += (size_t)64*KD*2;
  f16* WueL = (f16*)p; p += (size_t)64*KD*2;
  f16* WgdH = (f16*)p; p += (size_t)128*KD*2;
  f16* WgdL = (f16*)p; p += (size_t)128*KD*2;
  f16* WudH = (f16*)p; p += (size_t)64*KD*2;
  f16* WudL = (f16*)p; p += (size_t)64*KD*2;

  fold_w_t<<<(128*KD+255)/256, 256, 0, stream>>>(egW, WgeH, WgeL, 65, 128);
  fold_w_t<<<(64*KD +255)/256, 256, 0, stream>>>(euW, WueH, WueL, 65, 64);
  fold_w_t<<<(128*KD+255)/256, 256, 0, stream>>>(dgW, WgdH, WgdL, 66, 128);
  fold_w_t<<<(64*KD +255)/256, 256, 0, stream>>>(duW, WudH, WudL, 66, 64);

  softmax_graph<<<64, 512, 0, stream>>>(ne, 0, AsH, AsL, 0);
  sq_mm<<<dim3(8,8,1), 256, 0, stream>>>(AsH, AsL, 0, As2H, As2L, 0);
  (void)hipMemsetAsync(h, 0, (size_t)RS*HH*4, stream);
  (void)hipMemsetAsync(XaRH, 0, (size_t)RS*XS*2*8, stream);  // all 8 X arrays contiguous
  fill_col<<<(RS+255)/256, 256, 0, stream>>>(XaRH, XaRL, XaCH, XaCL, 0, x, (long long)TTNN);

  GruP Pe{AsH, AsL, As2H, As2L, 0,
          XaRH,XaRL,XaCH,XaCL, XbRH,XbRL,XbCH,XbCL,
          WgeH,WgeL,WueH,WueL, egb,eub, h,rb,
          x,ycov,pW,pb,out};
  void* argsE[] = { &Pe };
  (void)hipLaunchCooperativeKernel((const void*)&gru_seq<0>, dim3(NB,8), dim3(512),
                                   argsE, 0, stream);

  edyn_k<<<RS/4, 256, 0, stream>>>(h, ne, hW, hb, Ed);
  softmax_graph<<<NB*64, 512, 0, stream>>>(Ed, (long long)NN*EE, AdH, AdL, (long long)NN*NN);
  sq_mm<<<dim3(8,8,NB), 256, 0, stream>>>(AdH, AdL, (long long)NN*NN, Ad2H, Ad2L, (long long)NN*NN);

  GruP Pd{AdH, AdL, Ad2H, Ad2L, (long long)NN*NN,
          XaRH,XaRL,XaCH,XaCL, XbRH,XbRL,XbCH,XbCL,
          WgdH,WgdL,WudH,WudL, dgb,dub, h,rb,
          x,ycov,pW,pb,out};
  void* argsD[] = { &Pd };
  (void)hipLaunchCooperativeKernel((const void*)&gru_seq<1>, dim3(NB,8), dim3(512),
                                   argsD, 0, stream);
}

// Round 16
// 1737.497 us; speedup vs baseline: 1.9173x; 1.9173x over previous
//
#include <hip/hip_runtime.h>

#define NB 32
#define TT 12
#define NN 512
#define HH 64
#define EE 10
#define XS 80       // X row width (halves)
#define KD 240      // dense K = 3*80
#define RS (NB*NN)  // 16384 global rows
#define TTNN (TT*NN)
#define GP 164

typedef _Float16 f16;
typedef __attribute__((ext_vector_type(4))) _Float16 f16x4;
typedef __attribute__((ext_vector_type(8))) _Float16 f16x8;
typedef __attribute__((ext_vector_type(4))) float f32x4;

#define MFMA32(a,bb,c) __builtin_amdgcn_mfma_f32_16x16x32_f16(a,bb,c,0,0,0)
#define MFMA16(a,bb,c) __builtin_amdgcn_mfma_f32_16x16x16f16(a,bb,c,0,0,0)

__device__ __forceinline__ void barrier_lgkm() {
  asm volatile("s_waitcnt lgkmcnt(0)" ::: "memory");
  __builtin_amdgcn_s_barrier();
  __builtin_amdgcn_sched_barrier(0);
}

union SMem {
  struct {
    f16 PsH[2][2][64][32], PsL[2][2][64][32];  // [buf][A=0/A2=1][row][k]
    f16 XtH[2][80][40], XtL[2][80][40];        // [buf][col][k]
  } s1;
  struct {
    f16 gH[64][GP], gL[64][GP];                // [row][g1|g2]
  } s2;
};

// ---------------- fold Chebyshev into weights; transpose to [O][KD]; f16 split ----
__global__ void fold_w_t(const float* __restrict__ src, f16* __restrict__ WtH,
                         f16* __restrict__ WtL, int C, int O){
  int idx = blockIdx.x*256 + threadIdx.x;
  if (idx >= O*KD) return;
  int o = idx / KD;
  int k = idx % KD;
  int s = k / XS, c = k % XS;
  float v = 0.f;
  if (c < C) {
    if (s == 0)      v = src[c*O+o] - src[(2*C+c)*O+o];
    else if (s == 1) v = src[(C+c)*O+o];
    else             v = 2.f*src[(2*C+c)*O+o];
  }
  f16 hi = (f16)v;
  WtH[idx] = hi;
  WtL[idx] = (f16)(v - (float)hi);
}

// ---------------- A = softmax(relu(E E^T)): 8 rows/block, wave-per-row ----------
__global__ __launch_bounds__(512) void softmax_graph(
    const float* __restrict__ Emb, long long ebs,
    f16* __restrict__ AH, f16* __restrict__ AL, long long abs_)
{
  __shared__ float Es[NN*EE];
  int b  = blockIdx.x >> 6;
  int rt = blockIdx.x & 63;
  const float* Eb = Emb + (long long)b*ebs;
  int tid = threadIdx.x;
  for (int i = tid; i < NN*EE; i += 512) Es[i] = Eb[i];
  __syncthreads();
  int wave = tid >> 6, lane = tid & 63;
  int r = rt*8 + wave;
  float q[EE];
  #pragma unroll
  for (int e = 0; e < EE; ++e) q[e] = Es[r*EE + e];
  float sv[8];
  float mx = 0.f;
  #pragma unroll
  for (int j = 0; j < 8; ++j) {
    int m = 64*j + lane;
    float s = 0.f;
    #pragma unroll
    for (int e = 0; e < EE; ++e) s += q[e]*Es[m*EE + e];
    s = fmaxf(s, 0.f);
    sv[j] = s;
    mx = fmaxf(mx, s);
  }
  #pragma unroll
  for (int off = 32; off >= 1; off >>= 1) mx = fmaxf(mx, __shfl_xor(mx, off, 64));
  float sm = 0.f;
  #pragma unroll
  for (int j = 0; j < 8; ++j) { sv[j] = expf(sv[j] - mx); sm += sv[j]; }
  #pragma unroll
  for (int off = 32; off >= 1; off >>= 1) sm += __shfl_xor(sm, off, 64);
  float inv = 1.f / sm;
  #pragma unroll
  for (int j = 0; j < 8; ++j) {
    int m = 64*j + lane;
    float p = sv[j] * inv;
    long long o = (long long)b*abs_ + (long long)r*NN + m;
    f16 hi = (f16)p;
    AH[o] = hi;
    AL[o] = (f16)(p - (float)hi);
  }
}

// ---------------- B = A @ A (per batch), f16-split 3-product ---------------------
__global__ __launch_bounds__(256) void sq_mm(
    const f16* __restrict__ AH, const f16* __restrict__ AL, long long astr,
    f16* __restrict__ BH, f16* __restrict__ BL, long long bstr)
{
  __shared__ f16 RsH[64][36], RsL[64][36], CsH[64][34], CsL[64][34];
  int b = blockIdx.z;
  int rows0 = blockIdx.y*64, cols0 = blockIdx.x*64;
  const f16* Ah = AH + (long long)b*astr;
  const f16* Al = AL + (long long)b*astr;
  int tid = threadIdx.x, l = tid & 63, w = tid >> 6, lr = l & 15, lg = l >> 4;
  int ar = w*16 + lr;
  int st_row = tid >> 2, st_seg = tid & 3;
  int sx_m = tid >> 3, sx_sub = tid & 7;
  f32x4 acc[4] = {};
  for (int kt = 0; kt < 16; ++kt) {
    int k0 = kt*32;
    barrier_lgkm();
    {
      f16x8 vh = *(const f16x8*)&Ah[(long long)(rows0+st_row)*NN + k0 + 8*st_seg];
      f16x8 vl = *(const f16x8*)&Al[(long long)(rows0+st_row)*NN + k0 + 8*st_seg];
      *(f16x8*)&RsH[st_row][8*st_seg] = vh;
      *(f16x8*)&RsL[st_row][8*st_seg] = vl;
    }
    #pragma unroll
    for (int j = 0; j < 2; ++j) {
      int c4 = sx_sub + 8*j;   // 0..15
      f16x4 vh = *(const f16x4*)&Ah[(long long)(k0+sx_m)*NN + cols0 + 4*c4];
      f16x4 vl = *(const f16x4*)&Al[(long long)(k0+sx_m)*NN + cols0 + 4*c4];
      #pragma unroll
      for (int q = 0; q < 4; ++q) {
        CsH[4*c4+q][sx_m] = vh[q];
        CsL[4*c4+q][sx_m] = vl[q];
      }
    }
    barrier_lgkm();
    f16x8 a_h = *(const f16x8*)&RsH[ar][8*lg];
    f16x8 a_l = *(const f16x8*)&RsL[ar][8*lg];
    #pragma unroll
    for (int cf = 0; cf < 4; ++cf) {
      int c = cf*16 + lr;
      f16x8 b_h = *(const f16x8*)&CsH[c][8*lg];
      f16x8 b_l = *(const f16x8*)&CsL[c][8*lg];
      acc[cf] = MFMA32(a_h, b_h, acc[cf]);
      acc[cf] = MFMA32(a_h, b_l, acc[cf]);
      acc[cf] = MFMA32(a_l, b_h, acc[cf]);
    }
  }
  #pragma unroll
  for (int cf = 0; cf < 4; ++cf) {
    #pragma unroll
    for (int reg = 0; reg < 4; ++reg) {
      int r = rows0 + w*16 + lg*4 + reg;
      int c = cols0 + cf*16 + lr;
      float v = acc[cf][reg];
      f16 hi = (f16)v;
      long long o = (long long)b*bstr + (long long)r*NN + c;
      BH[o] = hi;
      BL[o] = (f16)(v - (float)hi);
    }
  }
}

// ---------------- write one special column of X (dual layout, split) -------------
__global__ void fill_col(f16* __restrict__ XRH, f16* __restrict__ XRL,
                         f16* __restrict__ XCH, f16* __restrict__ XCL, int col,
                         const float* __restrict__ src, long long sstr){
  int row = blockIdx.x*256 + threadIdx.x;
  if (row >= RS) return;
  float v = src[(long long)(row>>9)*sstr + (row & 511)];
  f16 hi = (f16)v;
  f16 lo = (f16)(v - (float)hi);
  XRH[(long long)row*XS + col] = hi;
  XRL[(long long)row*XS + col] = lo;
  XCH[(long long)col*RS + row] = hi;
  XCL[(long long)col*RS + row] = lo;
}

// ---------------- fused half-step: A staged via global_load_lds + counted vmcnt --
template<int GATE, int DEC>
__global__ __launch_bounds__(512, 2) void fused_half(
    const f16* __restrict__ AH, const f16* __restrict__ AL,
    const f16* __restrict__ A2H, const f16* __restrict__ A2L, long long astr,
    const f16* __restrict__ XiRH, const f16* __restrict__ XiRL,
    const f16* __restrict__ XiCH, const f16* __restrict__ XiCL,
    f16* __restrict__ XoRH, f16* __restrict__ XoRL,
    f16* __restrict__ XoCH, f16* __restrict__ XoCL,
    const f16* __restrict__ WH, const f16* __restrict__ WL,
    const float* __restrict__ bias,
    float* __restrict__ hbuf, float* __restrict__ rb,
    const float* __restrict__ pWv, const float* __restrict__ pbv,
    float* __restrict__ outp, int t,
    const float* __restrict__ s0src, const float* __restrict__ s1src,
    int ns, int ns_next, int writeX)
{
  __shared__ SMem sm;
  __shared__ float gpart[64];
  const int b = blockIdx.x;
  const int rows0 = blockIdx.y * 64;
  const long long bNN = (long long)b*NN;
  const int tid = threadIdx.x;
  const int w = tid >> 6, l = tid & 63;
  const int lr = l & 15, lg = l >> 4;
  const int grp = w >> 2;
  const int w4 = w & 3;
  const int ar = w4*16 + lr;
  const int asw = (ar >> 2) & 3;

  // A staging via global_load_lds: wave w covers rows jj*16..+15 of matrix grp.
  // Pre-swizzled global source reproduces the XOR'd LDS image with a linear dest.
  const int arow_st = w4*16 + (l >> 2);               // 0..63
  const int aseg_st = (l & 3) ^ ((arow_st >> 2) & 3); // pre-swizzled segment
  const f16* GgH = (grp ? A2H : AH) + (long long)b*astr
                 + (long long)(rows0 + arow_st)*NN + 8*aseg_st;
  const f16* GgL = (grp ? A2L : AL) + (long long)b*astr
                 + (long long)(rows0 + arow_st)*NN + 8*aseg_st;

  // X staging mapping (col-major source)
  const int xc = tid >> 3;
  const int xsub = tid & 7;
  const int xa = xsub >> 2;
  const int xo = xsub & 3;
  const int xc2 = (tid < 128) ? (64 + xc) : 64;
  const f16* XC1 = (xa ? XiCL : XiCH) + (long long)xc*RS + bNN;
  const f16* XC2 = (xa ? XiCL : XiCH) + (long long)xc2*RS + bNN;

  f16x8 xA1{}, xA2{}, xB1{}, xB2{};

  auto GLOADA = [&](int kt, int buf){
    __builtin_amdgcn_global_load_lds(
        (const __attribute__((address_space(1))) void*)(GgH + kt*32),
        (__attribute__((address_space(3))) void*)&sm.s1.PsH[buf][grp][w4*16][0],
        16, 0, 0);
    __builtin_amdgcn_global_load_lds(
        (const __attribute__((address_space(1))) void*)(GgL + kt*32),
        (__attribute__((address_space(3))) void*)&sm.s1.PsL[buf][grp][w4*16][0],
        16, 0, 0);
  };
  auto LOADX = [&](int kt, f16x8& x1, f16x8& x2){
    int k0 = kt*32;
    x1 = *(const f16x8*)&XC1[k0 + 8*xo];
    if (tid < 128) x2 = *(const f16x8*)&XC2[k0 + 8*xo];
  };
  auto STOREX = [&](int buf, f16x8& x1, f16x8& x2){
    f16 (*xt)[40] = xa ? sm.s1.XtL[buf] : sm.s1.XtH[buf];
    *(f16x8*)&xt[xc][8*xo] = x1;
    if (tid < 128) *(f16x8*)&xt[64 + xc][8*xo] = x2;
  };
  // Counted-vmcnt barrier: per wave, only this interval's X loads (2 for waves
  // 0-1, 1 for waves 2-7) were issued after the gloads we must wait for.
  auto WAITB = [&](){
    if (tid < 128) asm volatile("s_waitcnt vmcnt(2)" ::: "memory");
    else           asm volatile("s_waitcnt vmcnt(1)" ::: "memory");
    asm volatile("s_waitcnt lgkmcnt(0)" ::: "memory");
    __builtin_amdgcn_s_barrier();
    __builtin_amdgcn_sched_barrier(0);
  };
  f32x4 acc[5] = {};
  auto COMP = [&](int buf){
    int sa = 8*(lg ^ asw);
    f16x8 ah  = *(const f16x8*)&sm.s1.PsH[buf][grp][ar][sa];
    f16x8 al2 = *(const f16x8*)&sm.s1.PsL[buf][grp][ar][sa];
    __builtin_amdgcn_s_setprio(1);
    #pragma unroll
    for (int cf = 0; cf < 5; ++cf) {
      int c = cf*16 + lr;
      f16x8 bh = *(const f16x8*)&sm.s1.XtH[buf][c][8*lg];
      f16x8 bl = *(const f16x8*)&sm.s1.XtL[buf][c][8*lg];
      acc[cf] = MFMA32(ah, bh, acc[cf]);
      acc[cf] = MFMA32(ah, bl, acc[cf]);
      acc[cf] = MFMA32(al2, bh, acc[cf]);
    }
    __builtin_amdgcn_s_setprio(0);
  };

  // ---- prologue: prime buf0 fully, issue A(1) async ----
  LOADX(0, xA1, xA2);
  LOADX(1, xB1, xB2);
  GLOADA(0, 0);
  STOREX(0, xA1, xA2);
  asm volatile("s_waitcnt vmcnt(0)" ::: "memory");
  asm volatile("s_waitcnt lgkmcnt(0)" ::: "memory");
  __builtin_amdgcn_s_barrier();
  __builtin_amdgcn_sched_barrier(0);
  GLOADA(1, 1);

  #pragma unroll
  for (int kt2 = 0; kt2 < 8; ++kt2) {
    const int kt = kt2*2;
    // iter A: compute A(kt) from buf0
    COMP(0);
    STOREX(1, xB1, xB2);                    // X(kt+1) -> buf1
    if (kt+2 < 16) LOADX(kt+2, xA1, xA2);
    WAITB();                                // buf1 ready (A gload + X writes)
    if (kt+2 < 16) GLOADA(kt+2, 0);
    // iter B: compute A(kt+1) from buf1
    COMP(1);
    if (kt+2 < 16) {
      STOREX(0, xA1, xA2);                  // X(kt+2) -> buf0
      if (kt+3 < 16) LOADX(kt+3, xB1, xB2);
      WAITB();                              // buf0 ready
      if (kt+3 < 16) GLOADA(kt+3, 1);
    }
  }
  barrier_lgkm();   // all waves done with s1 before union reuse

  // ---- dump g (split) into LDS union ----
  {
    int go_ = grp*80;
    #pragma unroll
    for (int cf = 0; cf < 5; ++cf) {
      int col = go_ + cf*16 + lr;
      #pragma unroll
      for (int reg = 0; reg < 4; ++reg) {
        int row = w4*16 + lg*4 + reg;
        float v = acc[cf][reg];
        f16 hi = (f16)v;
        sm.s2.gH[row][col] = hi;
        sm.s2.gL[row][col] = (f16)(v - (float)hi);
      }
    }
  }
  barrier_lgkm();

  // ---- dense: K = [x(rm global) | g1(LDS) | g2(LDS)], W from global ----
  constexpr int CFW = GATE ? 4 : 2;
  f32x4 accD[CFW] = {};
  const long long grow0 = bNN + rows0 + w4*16;
  const f16* xrH = XiRH + (grow0 + lr)*XS;
  const f16* xrL = XiRL + (grow0 + lr)*XS;
  #pragma unroll
  for (int c = 0; c < 15; ++c) {
    f16x4 a_h, a_l;
    if (c < 5) {
      a_h = *(const f16x4*)&xrH[c*16 + 4*lg];
      a_l = *(const f16x4*)&xrL[c*16 + 4*lg];
    } else {
      int gk = (c-5)*16 + 4*lg;
      a_h = *(const f16x4*)&sm.s2.gH[w4*16 + lr][gk];
      a_l = *(const f16x4*)&sm.s2.gL[w4*16 + lr][gk];
    }
    #pragma unroll
    for (int cf = 0; cf < CFW; ++cf) {
      int o = grp*(CFW*16) + cf*16 + lr;
      f16x4 b_h = *(const f16x4*)&WH[(long long)o*KD + c*16 + 4*lg];
      f16x4 b_l = *(const f16x4*)&WL[(long long)o*KD + c*16 + 4*lg];
      accD[cf] = MFMA16(a_h, b_h, accD[cf]);
      accD[cf] = MFMA16(a_h, b_l, accD[cf]);
      accD[cf] = MFMA16(a_l, b_h, accD[cf]);
    }
  }

  // ---- epilogue ----
  if constexpr (GATE) {
    #pragma unroll
    for (int cf = 0; cf < CFW; ++cf) {
      int o = grp*64 + cf*16 + lr;
      float bi = bias[o];
      #pragma unroll
      for (int reg = 0; reg < 4; ++reg) {
        long long grow = grow0 + lg*4 + reg;
        float v = 1.f/(1.f + expf(-(accD[cf][reg] + bi)));
        if (grp == 0) {
          float zh = v * hbuf[grow*HH + o];
          f16 hi = (f16)zh; f16 lo = (f16)(zh - (float)hi);
          XoRH[grow*XS + ns + o] = hi; XoRL[grow*XS + ns + o] = lo;
          XoCH[(long long)(ns+o)*RS + grow] = hi; XoCL[(long long)(ns+o)*RS + grow] = lo;
        } else {
          rb[grow*HH + (o - HH)] = v;
        }
      }
    }
    if (grp == 0 && lr < ns) {
      #pragma unroll
      for (int reg = 0; reg < 4; ++reg) {
        long long grow = grow0 + lg*4 + reg;
        f16 vh = XiRH[grow*XS + lr], vl = XiRL[grow*XS + lr];
        XoRH[grow*XS + lr] = vh; XoRL[grow*XS + lr] = vl;
        XoCH[(long long)lr*RS + grow] = vh; XoCL[(long long)lr*RS + grow] = vl;
      }
    }
  } else {
    float gop[4] = {0.f,0.f,0.f,0.f};
    #pragma unroll
    for (int cf = 0; cf < CFW; ++cf) {
      int o = grp*32 + cf*16 + lr;
      float bi = bias[o];
      float pwv = 0.f;
      if constexpr (DEC) pwv = pWv[o];
      #pragma unroll
      for (int reg = 0; reg < 4; ++reg) {
        long long grow = grow0 + lg*4 + reg;
        float hc = tanhf(accD[cf][reg] + bi);
        float rv = rb[grow*HH + o];
        float hv = hbuf[grow*HH + o];
        float hn = rv*hv + (1.f - rv)*hc;
        hbuf[grow*HH + o] = hn;
        if (writeX) {
          f16 hi = (f16)hn; f16 lo = (f16)(hn - (float)hi);
          XoRH[grow*XS + ns_next + o] = hi; XoRL[grow*XS + ns_next + o] = lo;
          XoCH[(long long)(ns_next+o)*RS + grow] = hi; XoCL[(long long)(ns_next+o)*RS + grow] = lo;
        }
        if constexpr (DEC) gop[reg] += hn * pwv;
      }
    }
    if constexpr (DEC) {
      #pragma unroll
      for (int reg = 0; reg < 4; ++reg) {
        #pragma unroll
        for (int off = 8; off >= 1; off >>= 1)
          gop[reg] += __shfl_xor(gop[reg], off, 64);
      }
      if (grp == 1 && lr == 0) {
        #pragma unroll
        for (int reg = 0; reg < 4; ++reg)
          gpart[w4*16 + lg*4 + reg] = gop[reg];
      }
      barrier_lgkm();
      if (grp == 0 && lr == 0) {
        float pb0 = pbv[0];
        #pragma unroll
        for (int reg = 0; reg < 4; ++reg) {
          int n = rows0 + w4*16 + lg*4 + reg;
          long long grow = bNN + n;
          float go = gop[reg] + gpart[w4*16 + lg*4 + reg] + pb0;
          outp[((long long)b*TT + t)*NN + n] = go;
          if (writeX) {
            f16 hi = (f16)go; f16 lo = (f16)(go - (float)hi);
            XoRH[grow*XS] = hi; XoRL[grow*XS] = lo;
            XoCH[grow] = hi; XoCL[grow] = lo;
            float yv = s1src[(long long)b*TTNN + n];
            f16 hy = (f16)yv; f16 ly = (f16)(yv - (float)hy);
            XoRH[grow*XS + 1] = hy; XoRL[grow*XS + 1] = ly;
            XoCH[RS + grow] = hy; XoCL[RS + grow] = ly;
          }
        }
      }
    } else {
      if (writeX && grp == 0 && lr == 0) {
        #pragma unroll
        for (int reg = 0; reg < 4; ++reg) {
          int n = rows0 + w4*16 + lg*4 + reg;
          long long grow = bNN + n;
          float v0 = s0src ? s0src[(long long)b*TTNN + n] : 0.f;
          f16 h0 = (f16)v0; f16 l0 = (f16)(v0 - (float)h0);
          XoRH[grow*XS] = h0; XoRL[grow*XS] = l0;
          XoCH[grow] = h0; XoCL[grow] = l0;
          if (ns_next == 2 && s1src) {
            float v1 = s1src[(long long)b*TTNN + n];
            f16 h1 = (f16)v1; f16 l1 = (f16)(v1 - (float)h1);
            XoRH[grow*XS + 1] = h1; XoRL[grow*XS + 1] = l1;
            XoCH[RS + grow] = h1; XoCL[RS + grow] = l1;
          }
        }
      }
    }
  }
}

// ---------------- E_dyn = ne + h @ hyper_W + hyper_b -----------------------------
__global__ __launch_bounds__(256) void edyn_k(
    const float* __restrict__ h, const float* __restrict__ ne,
    const float* __restrict__ hW, const float* __restrict__ hb, float* __restrict__ Ed)
{
  int row = blockIdx.x*4 + (threadIdx.x >> 6);
  int lane = threadIdx.x & 63;
  float hv = h[(long long)row*HH + lane];
  float myval = 0.f;
  #pragma unroll
  for (int e = 0; e < EE; ++e) {
    float v = hv * hW[lane*EE + e];
    #pragma unroll
    for (int off = 32; off >= 1; off >>= 1) v += __shfl_xor(v, off, 64);
    if (lane == e) myval = v;
  }
  if (lane < EE) {
    int n = row & 511;
    Ed[(long long)row*EE + lane] = ne[n*EE + lane] + hb[lane] + myval;
  }
}

extern "C" void kernel_launch(void* const* d_in, const int* in_sizes, int n_in,
                              void* d_out, int out_size, void* d_ws, size_t ws_size,
                              hipStream_t stream)
{
  const float* x    = (const float*)d_in[0];
  const float* ycov = (const float*)d_in[1];
  const float* ne   = (const float*)d_in[2];
  const float* egW  = (const float*)d_in[3];
  const float* egb  = (const float*)d_in[4];
  const float* euW  = (const float*)d_in[5];
  const float* eub  = (const float*)d_in[6];
  const float* dgW  = (const float*)d_in[7];
  const float* dgb  = (const float*)d_in[8];
  const float* duW  = (const float*)d_in[9];
  const float* dub  = (const float*)d_in[10];
  const float* pW   = (const float*)d_in[11];
  const float* pb   = (const float*)d_in[12];
  const float* hW   = (const float*)d_in[13];
  const float* hb   = (const float*)d_in[14];
  float* out = (float*)d_out;

  char* p = (char*)d_ws;
  f16* AsH  = (f16*)p; p += (size_t)NN*NN*2;
  f16* AsL  = (f16*)p; p += (size_t)NN*NN*2;
  f16* As2H = (f16*)p; p += (size_t)NN*NN*2;
  f16* As2L = (f16*)p; p += (size_t)NN*NN*2;
  f16* AdH  = (f16*)p; p += (size_t)NB*NN*NN*2;
  f16* AdL  = (f16*)p; p += (size_t)NB*NN*NN*2;
  f16* Ad2H = (f16*)p; p += (size_t)NB*NN*NN*2;
  f16* Ad2L = (f16*)p; p += (size_t)NB*NN*NN*2;
  f16* XaRH = (f16*)p; p += (size_t)RS*XS*2;
  f16* XaRL = (f16*)p; p += (size_t)RS*XS*2;
  f16* XaCH = (f16*)p; p += (size_t)RS*XS*2;
  f16* XaCL = (f16*)p; p += (size_t)RS*XS*2;
  f16* XbRH = (f16*)p; p += (size_t)RS*XS*2;
  f16* XbRL = (f16*)p; p += (size_t)RS*XS*2;
  f16* XbCH = (f16*)p; p += (size_t)RS*XS*2;
  f16* XbCL = (f16*)p; p += (size_t)RS*XS*2;
  float* h  = (float*)p; p += (size_t)RS*HH*4;
  float* rb = (float*)p; p += (size_t)RS*HH*4;
  float* Ed = (float*)p; p += (size_t)RS*EE*4;
  f16* WgeH = (f16*)p; p += (size_t)128*KD*2;
  f16* WgeL = (f16*)p; p += (size_t)128*KD*2;
  f16* WueH = (f16*)p; p += (size_t)64*KD*2;
  f16* WueL = (f16*)p; p += (size_t)64*KD*2;
  f16* WgdH = (f16*)p; p += (size_t)128*KD*2;
  f16* WgdL = (f16*)p; p += (size_t)128*KD*2;
  f16* WudH = (f16*)p; p += (size_t)64*KD*2;
  f16* WudL = (f16*)p; p += (size_t)64*KD*2;

  fold_w_t<<<(128*KD+255)/256, 256, 0, stream>>>(egW, WgeH, WgeL, 65, 128);
  fold_w_t<<<(64*KD +255)/256, 256, 0, stream>>>(euW, WueH, WueL, 65, 64);
  fold_w_t<<<(128*KD+255)/256, 256, 0, stream>>>(dgW, WgdH, WgdL, 66, 128);
  fold_w_t<<<(64*KD +255)/256, 256, 0, stream>>>(duW, WudH, WudL, 66, 64);

  softmax_graph<<<64, 512, 0, stream>>>(ne, 0, AsH, AsL, 0);
  sq_mm<<<dim3(8,8,1), 256, 0, stream>>>(AsH, AsL, 0, As2H, As2L, 0);
  (void)hipMemsetAsync(h, 0, (size_t)RS*HH*4, stream);
  (void)hipMemsetAsync(XaRH, 0, (size_t)RS*XS*2*8, stream);  // all 8 X arrays contiguous
  fill_col<<<(RS+255)/256, 256, 0, stream>>>(XaRH, XaRL, XaCH, XaCL, 0, x, (long long)TTNN);

  dim3 fgrid(NB, 8);
  for (int t = 0; t < TT; ++t) {
    fused_half<1,0><<<fgrid, 512, 0, stream>>>(
        AsH, AsL, As2H, As2L, 0,
        XaRH, XaRL, XaCH, XaCL, XbRH, XbRL, XbCH, XbCL,
        WgeH, WgeL, egb, h, rb, nullptr, nullptr, nullptr, t,
        nullptr, nullptr, 1, 0, 1);
    fused_half<0,0><<<fgrid, 512, 0, stream>>>(
        AsH, AsL, As2H, As2L, 0,
        XbRH, XbRL, XbCH, XbCL, XaRH, XaRL, XaCH, XaCL,
        WueH, WueL, eub, h, rb, nullptr, nullptr, nullptr, t,
        (t < TT-1 ? x + (size_t)(t+1)*NN : nullptr),
        (t < TT-1 ? nullptr : ycov),
        1, (t < TT-1 ? 1 : 2), 1);
  }

  edyn_k<<<RS/4, 256, 0, stream>>>(h, ne, hW, hb, Ed);
  softmax_graph<<<NB*64, 512, 0, stream>>>(Ed, (long long)NN*EE, AdH, AdL, (long long)NN*NN);
  sq_mm<<<dim3(8,8,NB), 256, 0, stream>>>(AdH, AdL, (long long)NN*NN, Ad2H, Ad2L, (long long)NN*NN);

  for (int t = 0; t < TT; ++t) {
    fused_half<1,1><<<fgrid, 512, 0, stream>>>(
        AdH, AdL, Ad2H, Ad2L, (long long)NN*NN,
        XaRH, XaRL, XaCH, XaCL, XbRH, XbRL, XbCH, XbCL,
        WgdH, WgdL, dgb, h, rb, nullptr, nullptr, nullptr, t,
        nullptr, nullptr, 2, 0, 1);
    fused_half<0,1><<<fgrid, 512, 0, stream>>>(
        AdH, AdL, Ad2H, Ad2L, (long long)NN*NN,
        XbRH, XbRL, XbCH, XbCL, XaRH, XaRL, XaCH, XaCL,
        WudH, WudL, dub, h, rb, pW, pb, out, t,
        nullptr, (t < TT-1 ? ycov + (size_t)(t+1)*NN : nullptr),
        2, 2, (t < TT-1 ? 1 : 0));
  }
}

// Round 17
// 1616.909 us; speedup vs baseline: 2.0603x; 1.0746x over previous
//
#include <hip/hip_runtime.h>

#define NB 32
#define TT 12
#define NN 512
#define HH 64
#define EE 10
#define XS 80       // X row width (halves)
#define KD 240      // dense K = 3*80
#define RS (NB*NN)  // 16384 global rows
#define TTNN (TT*NN)
#define GP 164

typedef _Float16 f16;
typedef __attribute__((ext_vector_type(4))) _Float16 f16x4;
typedef __attribute__((ext_vector_type(8))) _Float16 f16x8;
typedef __attribute__((ext_vector_type(4))) float f32x4;

#define MFMA32(a,bb,c) __builtin_amdgcn_mfma_f32_16x16x32_f16(a,bb,c,0,0,0)
#define MFMA16(a,bb,c) __builtin_amdgcn_mfma_f32_16x16x16f16(a,bb,c,0,0,0)

__device__ __forceinline__ void barrier_lgkm() {
  asm volatile("s_waitcnt lgkmcnt(0)" ::: "memory");
  __builtin_amdgcn_s_barrier();
  __builtin_amdgcn_sched_barrier(0);
}

union SMem {
  struct {
    f16 PsH[2][2][64][32], PsL[2][2][64][32];  // [buf][A=0/A2=1][row][k]
    f16 XtH[2][80][40], XtL[2][80][40];        // [buf][col][k]
  } s1;
  struct {
    f16 gH[64][GP], gL[64][GP];                // [row][g1|g2]
  } s2;
};

// ---------------- fold Chebyshev into weights; transpose to [O][KD]; f16 split ----
__global__ void fold_w_t(const float* __restrict__ src, f16* __restrict__ WtH,
                         f16* __restrict__ WtL, int C, int O){
  int idx = blockIdx.x*256 + threadIdx.x;
  if (idx >= O*KD) return;
  int o = idx / KD;
  int k = idx % KD;
  int s = k / XS, c = k % XS;
  float v = 0.f;
  if (c < C) {
    if (s == 0)      v = src[c*O+o] - src[(2*C+c)*O+o];
    else if (s == 1) v = src[(C+c)*O+o];
    else             v = 2.f*src[(2*C+c)*O+o];
  }
  f16 hi = (f16)v;
  WtH[idx] = hi;
  WtL[idx] = (f16)(v - (float)hi);
}

// ---------------- A = softmax(relu(E E^T)): 8 rows/block, wave-per-row ----------
__global__ __launch_bounds__(512) void softmax_graph(
    const float* __restrict__ Emb, long long ebs,
    f16* __restrict__ AH, f16* __restrict__ AL, long long abs_)
{
  __shared__ float Es[NN*EE];
  int b  = blockIdx.x >> 6;
  int rt = blockIdx.x & 63;
  const float* Eb = Emb + (long long)b*ebs;
  int tid = threadIdx.x;
  for (int i = tid; i < NN*EE; i += 512) Es[i] = Eb[i];
  __syncthreads();
  int wave = tid >> 6, lane = tid & 63;
  int r = rt*8 + wave;
  float q[EE];
  #pragma unroll
  for (int e = 0; e < EE; ++e) q[e] = Es[r*EE + e];
  float sv[8];
  float mx = 0.f;
  #pragma unroll
  for (int j = 0; j < 8; ++j) {
    int m = 64*j + lane;
    float s = 0.f;
    #pragma unroll
    for (int e = 0; e < EE; ++e) s += q[e]*Es[m*EE + e];
    s = fmaxf(s, 0.f);
    sv[j] = s;
    mx = fmaxf(mx, s);
  }
  #pragma unroll
  for (int off = 32; off >= 1; off >>= 1) mx = fmaxf(mx, __shfl_xor(mx, off, 64));
  float sm = 0.f;
  #pragma unroll
  for (int j = 0; j < 8; ++j) { sv[j] = expf(sv[j] - mx); sm += sv[j]; }
  #pragma unroll
  for (int off = 32; off >= 1; off >>= 1) sm += __shfl_xor(sm, off, 64);
  float inv = 1.f / sm;
  #pragma unroll
  for (int j = 0; j < 8; ++j) {
    int m = 64*j + lane;
    float p = sv[j] * inv;
    long long o = (long long)b*abs_ + (long long)r*NN + m;
    f16 hi = (f16)p;
    AH[o] = hi;
    AL[o] = (f16)(p - (float)hi);
  }
}

// ---------------- B = A @ A (per batch), f16-split input; BL optional -----------
__global__ __launch_bounds__(256) void sq_mm(
    const f16* __restrict__ AH, const f16* __restrict__ AL, long long astr,
    f16* __restrict__ BH, f16* __restrict__ BL, long long bstr)
{
  __shared__ f16 RsH[64][36], RsL[64][36], CsH[64][34], CsL[64][34];
  int b = blockIdx.z;
  int rows0 = blockIdx.y*64, cols0 = blockIdx.x*64;
  const f16* Ah = AH + (long long)b*astr;
  const f16* Al = AL + (long long)b*astr;
  int tid = threadIdx.x, l = tid & 63, w = tid >> 6, lr = l & 15, lg = l >> 4;
  int ar = w*16 + lr;
  int st_row = tid >> 2, st_seg = tid & 3;
  int sx_m = tid >> 3, sx_sub = tid & 7;
  f32x4 acc[4] = {};
  for (int kt = 0; kt < 16; ++kt) {
    int k0 = kt*32;
    barrier_lgkm();
    {
      f16x8 vh = *(const f16x8*)&Ah[(long long)(rows0+st_row)*NN + k0 + 8*st_seg];
      f16x8 vl = *(const f16x8*)&Al[(long long)(rows0+st_row)*NN + k0 + 8*st_seg];
      *(f16x8*)&RsH[st_row][8*st_seg] = vh;
      *(f16x8*)&RsL[st_row][8*st_seg] = vl;
    }
    #pragma unroll
    for (int j = 0; j < 2; ++j) {
      int c4 = sx_sub + 8*j;   // 0..15
      f16x4 vh = *(const f16x4*)&Ah[(long long)(k0+sx_m)*NN + cols0 + 4*c4];
      f16x4 vl = *(const f16x4*)&Al[(long long)(k0+sx_m)*NN + cols0 + 4*c4];
      #pragma unroll
      for (int q = 0; q < 4; ++q) {
        CsH[4*c4+q][sx_m] = vh[q];
        CsL[4*c4+q][sx_m] = vl[q];
      }
    }
    barrier_lgkm();
    f16x8 a_h = *(const f16x8*)&RsH[ar][8*lg];
    f16x8 a_l = *(const f16x8*)&RsL[ar][8*lg];
    #pragma unroll
    for (int cf = 0; cf < 4; ++cf) {
      int c = cf*16 + lr;
      f16x8 b_h = *(const f16x8*)&CsH[c][8*lg];
      f16x8 b_l = *(const f16x8*)&CsL[c][8*lg];
      acc[cf] = MFMA32(a_h, b_h, acc[cf]);
      acc[cf] = MFMA32(a_h, b_l, acc[cf]);
      acc[cf] = MFMA32(a_l, b_h, acc[cf]);
    }
  }
  #pragma unroll
  for (int cf = 0; cf < 4; ++cf) {
    #pragma unroll
    for (int reg = 0; reg < 4; ++reg) {
      int r = rows0 + w*16 + lg*4 + reg;
      int c = cols0 + cf*16 + lr;
      float v = acc[cf][reg];
      f16 hi = (f16)v;
      long long o = (long long)b*bstr + (long long)r*NN + c;
      BH[o] = hi;
      if (BL) BL[o] = (f16)(v - (float)hi);
    }
  }
}

// ---------------- write one special column of X (dual layout, split) -------------
__global__ void fill_col(f16* __restrict__ XRH, f16* __restrict__ XRL,
                         f16* __restrict__ XCH, f16* __restrict__ XCL, int col,
                         const float* __restrict__ src, long long sstr){
  int row = blockIdx.x*256 + threadIdx.x;
  if (row >= RS) return;
  float v = src[(long long)(row>>9)*sstr + (row & 511)];
  f16 hi = (f16)v;
  f16 lo = (f16)(v - (float)hi);
  XRH[(long long)row*XS + col] = hi;
  XRL[(long long)row*XS + col] = lo;
  XCH[(long long)col*RS + row] = hi;
  XCL[(long long)col*RS + row] = lo;
}

// ---------------- fused half-step; SPLITA: A stored/used as f16 H+L vs H only ---
template<int GATE, int DEC, int SPLITA>
__global__ __launch_bounds__(512, 2) void fused_half(
    const f16* __restrict__ AH, const f16* __restrict__ AL,
    const f16* __restrict__ A2H, const f16* __restrict__ A2L, long long astr,
    const f16* __restrict__ XiRH, const f16* __restrict__ XiRL,
    const f16* __restrict__ XiCH, const f16* __restrict__ XiCL,
    f16* __restrict__ XoRH, f16* __restrict__ XoRL,
    f16* __restrict__ XoCH, f16* __restrict__ XoCL,
    const f16* __restrict__ WH, const f16* __restrict__ WL,
    const float* __restrict__ bias,
    float* __restrict__ hbuf, float* __restrict__ rb,
    const float* __restrict__ pWv, const float* __restrict__ pbv,
    float* __restrict__ outp, int t,
    const float* __restrict__ s0src, const float* __restrict__ s1src,
    int ns, int ns_next, int writeX)
{
  __shared__ SMem sm;
  __shared__ float gpart[64];
  const int b = blockIdx.x;
  const int rows0 = blockIdx.y * 64;
  const long long bNN = (long long)b*NN;
  const int tid = threadIdx.x;
  const int w = tid >> 6, l = tid & 63;
  const int lr = l & 15, lg = l >> 4;
  const int grp = w >> 2;
  const int w4 = w & 3;
  const int ar = w4*16 + lr;
  const int asw = (ar >> 2) & 3;

  // A/A2 staging mapping: tid<256 stages A, tid>=256 stages A2
  const int stw = (tid < 256) ? 0 : 1;
  const int at = tid & 255;
  const int st_row = at >> 2, st_seg = at & 3;
  const int a_sw = (st_row >> 2) & 3;
  const f16* PgH = (stw ? A2H : AH) + (long long)b*astr + (long long)rows0*NN;
  const f16* PgL = SPLITA ? ((stw ? A2L : AL) + (long long)b*astr + (long long)rows0*NN)
                          : nullptr;

  // X staging mapping (col-major source)
  const int xc = tid >> 3;
  const int xsub = tid & 7;
  const int xa = xsub >> 2;
  const int xo = xsub & 3;
  const int xc2 = (tid < 128) ? (64 + xc) : 64;
  const f16* XC1 = (xa ? XiCL : XiCH) + (long long)xc*RS + bNN;
  const f16* XC2 = (xa ? XiCL : XiCH) + (long long)xc2*RS + bNN;

  f16x8 rH0{}, rL0{}, x10{}, x20{}, rH1{}, rL1{}, x11{}, x21{};

  auto LOAD = [&](int kt, f16x8& rH, f16x8& rL, f16x8& x1, f16x8& x2){
    int k0 = kt*32;
    long long ao = (long long)st_row*NN + k0 + 8*st_seg;
    rH = *(const f16x8*)&PgH[ao];
    if constexpr (SPLITA) rL = *(const f16x8*)&PgL[ao];
    x1 = *(const f16x8*)&XC1[k0 + 8*xo];
    if (tid < 128) x2 = *(const f16x8*)&XC2[k0 + 8*xo];
  };
  auto STORE = [&](int buf, f16x8& rH, f16x8& rL, f16x8& x1, f16x8& x2){
    int sc = 8*(st_seg ^ a_sw);
    *(f16x8*)&sm.s1.PsH[buf][stw][st_row][sc] = rH;
    if constexpr (SPLITA) *(f16x8*)&sm.s1.PsL[buf][stw][st_row][sc] = rL;
    f16 (*xt)[40] = xa ? sm.s1.XtL[buf] : sm.s1.XtH[buf];
    *(f16x8*)&xt[xc][8*xo] = x1;
    if (tid < 128) *(f16x8*)&xt[64 + xc][8*xo] = x2;
  };
  f32x4 acc[5] = {};
  auto COMP = [&](int buf){
    int sa = 8*(lg ^ asw);
    f16x8 ah = *(const f16x8*)&sm.s1.PsH[buf][grp][ar][sa];
    f16x8 al2{};
    if constexpr (SPLITA) al2 = *(const f16x8*)&sm.s1.PsL[buf][grp][ar][sa];
    __builtin_amdgcn_s_setprio(1);
    #pragma unroll
    for (int cf = 0; cf < 5; ++cf) {
      int c = cf*16 + lr;
      f16x8 bh = *(const f16x8*)&sm.s1.XtH[buf][c][8*lg];
      f16x8 bl = *(const f16x8*)&sm.s1.XtL[buf][c][8*lg];
      acc[cf] = MFMA32(ah, bh, acc[cf]);
      acc[cf] = MFMA32(ah, bl, acc[cf]);
      if constexpr (SPLITA) acc[cf] = MFMA32(al2, bh, acc[cf]);
    }
    __builtin_amdgcn_s_setprio(0);
  };

  LOAD(0, rH0,rL0,x10,x20);
  LOAD(1, rH1,rL1,x11,x21);
  STORE(0, rH0,rL0,x10,x20);
  barrier_lgkm();
  #pragma unroll
  for (int kt2 = 0; kt2 < 8; ++kt2) {
    int kt = kt2*2;
    if (kt+2 < 16) LOAD(kt+2, rH0,rL0,x10,x20);
    COMP(0);
    STORE(1, rH1,rL1,x11,x21);
    barrier_lgkm();
    if (kt+3 < 16) LOAD(kt+3, rH1,rL1,x11,x21);
    COMP(1);
    if (kt+2 < 16) STORE(0, rH0,rL0,x10,x20);
    barrier_lgkm();
  }

  // ---- dump g (split) into LDS union (staging dead after final barrier) ----
  {
    int go_ = grp*80;
    #pragma unroll
    for (int cf = 0; cf < 5; ++cf) {
      int col = go_ + cf*16 + lr;
      #pragma unroll
      for (int reg = 0; reg < 4; ++reg) {
        int row = w4*16 + lg*4 + reg;
        float v = acc[cf][reg];
        f16 hi = (f16)v;
        sm.s2.gH[row][col] = hi;
        sm.s2.gL[row][col] = (f16)(v - (float)hi);
      }
    }
  }
  barrier_lgkm();

  // ---- dense: K = [x(rm global) | g1(LDS) | g2(LDS)], W from global ----
  constexpr int CFW = GATE ? 4 : 2;
  f32x4 accD[CFW] = {};
  const long long grow0 = bNN + rows0 + w4*16;
  const f16* xrH = XiRH + (grow0 + lr)*XS;
  const f16* xrL = XiRL + (grow0 + lr)*XS;
  #pragma unroll
  for (int c = 0; c < 15; ++c) {
    f16x4 a_h, a_l;
    if (c < 5) {
      a_h = *(const f16x4*)&xrH[c*16 + 4*lg];
      a_l = *(const f16x4*)&xrL[c*16 + 4*lg];
    } else {
      int gk = (c-5)*16 + 4*lg;
      a_h = *(const f16x4*)&sm.s2.gH[w4*16 + lr][gk];
      a_l = *(const f16x4*)&sm.s2.gL[w4*16 + lr][gk];
    }
    #pragma unroll
    for (int cf = 0; cf < CFW; ++cf) {
      int o = grp*(CFW*16) + cf*16 + lr;
      f16x4 b_h = *(const f16x4*)&WH[(long long)o*KD + c*16 + 4*lg];
      f16x4 b_l = *(const f16x4*)&WL[(long long)o*KD + c*16 + 4*lg];
      accD[cf] = MFMA16(a_h, b_h, accD[cf]);
      accD[cf] = MFMA16(a_h, b_l, accD[cf]);
      accD[cf] = MFMA16(a_l, b_h, accD[cf]);
    }
  }

  // ---- epilogue ----
  if constexpr (GATE) {
    #pragma unroll
    for (int cf = 0; cf < CFW; ++cf) {
      int o = grp*64 + cf*16 + lr;
      float bi = bias[o];
      #pragma unroll
      for (int reg = 0; reg < 4; ++reg) {
        long long grow = grow0 + lg*4 + reg;
        float v = 1.f/(1.f + expf(-(accD[cf][reg] + bi)));
        if (grp == 0) {
          float zh = v * hbuf[grow*HH + o];
          f16 hi = (f16)zh; f16 lo = (f16)(zh - (float)hi);
          XoRH[grow*XS + ns + o] = hi; XoRL[grow*XS + ns + o] = lo;
          XoCH[(long long)(ns+o)*RS + grow] = hi; XoCL[(long long)(ns+o)*RS + grow] = lo;
        } else {
          rb[grow*HH + (o - HH)] = v;
        }
      }
    }
    if (grp == 0 && lr < ns) {
      #pragma unroll
      for (int reg = 0; reg < 4; ++reg) {
        long long grow = grow0 + lg*4 + reg;
        f16 vh = XiRH[grow*XS + lr], vl = XiRL[grow*XS + lr];
        XoRH[grow*XS + lr] = vh; XoRL[grow*XS + lr] = vl;
        XoCH[(long long)lr*RS + grow] = vh; XoCL[(long long)lr*RS + grow] = vl;
      }
    }
  } else {
    float gop[4] = {0.f,0.f,0.f,0.f};
    #pragma unroll
    for (int cf = 0; cf < CFW; ++cf) {
      int o = grp*32 + cf*16 + lr;
      float bi = bias[o];
      float pwv = 0.f;
      if constexpr (DEC) pwv = pWv[o];
      #pragma unroll
      for (int reg = 0; reg < 4; ++reg) {
        long long grow = grow0 + lg*4 + reg;
        float hc = tanhf(accD[cf][reg] + bi);
        float rv = rb[grow*HH + o];
        float hv = hbuf[grow*HH + o];
        float hn = rv*hv + (1.f - rv)*hc;
        hbuf[grow*HH + o] = hn;
        if (writeX) {
          f16 hi = (f16)hn; f16 lo = (f16)(hn - (float)hi);
          XoRH[grow*XS + ns_next + o] = hi; XoRL[grow*XS + ns_next + o] = lo;
          XoCH[(long long)(ns_next+o)*RS + grow] = hi; XoCL[(long long)(ns_next+o)*RS + grow] = lo;
        }
        if constexpr (DEC) gop[reg] += hn * pwv;
      }
    }
    if constexpr (DEC) {
      #pragma unroll
      for (int reg = 0; reg < 4; ++reg) {
        #pragma unroll
        for (int off = 8; off >= 1; off >>= 1)
          gop[reg] += __shfl_xor(gop[reg], off, 64);
      }
      if (grp == 1 && lr == 0) {
        #pragma unroll
        for (int reg = 0; reg < 4; ++reg)
          gpart[w4*16 + lg*4 + reg] = gop[reg];
      }
      barrier_lgkm();
      if (grp == 0 && lr == 0) {
        float pb0 = pbv[0];
        #pragma unroll
        for (int reg = 0; reg < 4; ++reg) {
          int n = rows0 + w4*16 + lg*4 + reg;
          long long grow = bNN + n;
          float go = gop[reg] + gpart[w4*16 + lg*4 + reg] + pb0;
          outp[((long long)b*TT + t)*NN + n] = go;
          if (writeX) {
            f16 hi = (f16)go; f16 lo = (f16)(go - (float)hi);
            XoRH[grow*XS] = hi; XoRL[grow*XS] = lo;
            XoCH[grow] = hi; XoCL[grow] = lo;
            float yv = s1src[(long long)b*TTNN + n];
            f16 hy = (f16)yv; f16 ly = (f16)(yv - (float)hy);
            XoRH[grow*XS + 1] = hy; XoRL[grow*XS + 1] = ly;
            XoCH[RS + grow] = hy; XoCL[RS + grow] = ly;
          }
        }
      }
    } else {
      if (writeX && grp == 0 && lr == 0) {
        #pragma unroll
        for (int reg = 0; reg < 4; ++reg) {
          int n = rows0 + w4*16 + lg*4 + reg;
          long long grow = bNN + n;
          float v0 = s0src ? s0src[(long long)b*TTNN + n] : 0.f;
          f16 h0 = (f16)v0; f16 l0 = (f16)(v0 - (float)h0);
          XoRH[grow*XS] = h0; XoRL[grow*XS] = l0;
          XoCH[grow] = h0; XoCL[grow] = l0;
          if (ns_next == 2 && s1src) {
            float v1 = s1src[(long long)b*TTNN + n];
            f16 h1 = (f16)v1; f16 l1 = (f16)(v1 - (float)h1);
            XoRH[grow*XS + 1] = h1; XoRL[grow*XS + 1] = l1;
            XoCH[RS + grow] = h1; XoCL[RS + grow] = l1;
          }
        }
      }
    }
  }
}

// ---------------- E_dyn = ne + h @ hyper_W + hyper_b -----------------------------
__global__ __launch_bounds__(256) void edyn_k(
    const float* __restrict__ h, const float* __restrict__ ne,
    const float* __restrict__ hW, const float* __restrict__ hb, float* __restrict__ Ed)
{
  int row = blockIdx.x*4 + (threadIdx.x >> 6);
  int lane = threadIdx.x & 63;
  float hv = h[(long long)row*HH + lane];
  float myval = 0.f;
  #pragma unroll
  for (int e = 0; e < EE; ++e) {
    float v = hv * hW[lane*EE + e];
    #pragma unroll
    for (int off = 32; off >= 1; off >>= 1) v += __shfl_xor(v, off, 64);
    if (lane == e) myval = v;
  }
  if (lane < EE) {
    int n = row & 511;
    Ed[(long long)row*EE + lane] = ne[n*EE + lane] + hb[lane] + myval;
  }
}

extern "C" void kernel_launch(void* const* d_in, const int* in_sizes, int n_in,
                              void* d_out, int out_size, void* d_ws, size_t ws_size,
                              hipStream_t stream)
{
  const float* x    = (const float*)d_in[0];
  const float* ycov = (const float*)d_in[1];
  const float* ne   = (const float*)d_in[2];
  const float* egW  = (const float*)d_in[3];
  const float* egb  = (const float*)d_in[4];
  const float* euW  = (const float*)d_in[5];
  const float* eub  = (const float*)d_in[6];
  const float* dgW  = (const float*)d_in[7];
  const float* dgb  = (const float*)d_in[8];
  const float* duW  = (const float*)d_in[9];
  const float* dub  = (const float*)d_in[10];
  const float* pW   = (const float*)d_in[11];
  const float* pb   = (const float*)d_in[12];
  const float* hW   = (const float*)d_in[13];
  const float* hb   = (const float*)d_in[14];
  float* out = (float*)d_out;

  char* p = (char*)d_ws;
  f16* AsH  = (f16*)p; p += (size_t)NN*NN*2;
  f16* AsL  = (f16*)p; p += (size_t)NN*NN*2;
  f16* As2H = (f16*)p; p += (size_t)NN*NN*2;
  f16* As2L = (f16*)p; p += (size_t)NN*NN*2;
  f16* AdH  = (f16*)p; p += (size_t)NB*NN*NN*2;
  f16* AdL  = (f16*)p; p += (size_t)NB*NN*NN*2;
  f16* Ad2H = (f16*)p; p += (size_t)NB*NN*NN*2;
  f16* XaRH = (f16*)p; p += (size_t)RS*XS*2;
  f16* XaRL = (f16*)p; p += (size_t)RS*XS*2;
  f16* XaCH = (f16*)p; p += (size_t)RS*XS*2;
  f16* XaCL = (f16*)p; p += (size_t)RS*XS*2;
  f16* XbRH = (f16*)p; p += (size_t)RS*XS*2;
  f16* XbRL = (f16*)p; p += (size_t)RS*XS*2;
  f16* XbCH = (f16*)p; p += (size_t)RS*XS*2;
  f16* XbCL = (f16*)p; p += (size_t)RS*XS*2;
  float* h  = (float*)p; p += (size_t)RS*HH*4;
  float* rb = (float*)p; p += (size_t)RS*HH*4;
  float* Ed = (float*)p; p += (size_t)RS*EE*4;
  f16* WgeH = (f16*)p; p += (size_t)128*KD*2;
  f16* WgeL = (f16*)p; p += (size_t)128*KD*2;
  f16* WueH = (f16*)p; p += (size_t)64*KD*2;
  f16* WueL = (f16*)p; p += (size_t)64*KD*2;
  f16* WgdH = (f16*)p; p += (size_t)128*KD*2;
  f16* WgdL = (f16*)p; p += (size_t)128*KD*2;
  f16* WudH = (f16*)p; p += (size_t)64*KD*2;
  f16* WudL = (f16*)p; p += (size_t)64*KD*2;

  fold_w_t<<<(128*KD+255)/256, 256, 0, stream>>>(egW, WgeH, WgeL, 65, 128);
  fold_w_t<<<(64*KD +255)/256, 256, 0, stream>>>(euW, WueH, WueL, 65, 64);
  fold_w_t<<<(128*KD+255)/256, 256, 0, stream>>>(dgW, WgdH, WgdL, 66, 128);
  fold_w_t<<<(64*KD +255)/256, 256, 0, stream>>>(duW, WudH, WudL, 66, 64);

  softmax_graph<<<64, 512, 0, stream>>>(ne, 0, AsH, AsL, 0);
  sq_mm<<<dim3(8,8,1), 256, 0, stream>>>(AsH, AsL, 0, As2H, As2L, 0);
  (void)hipMemsetAsync(h, 0, (size_t)RS*HH*4, stream);
  (void)hipMemsetAsync(XaRH, 0, (size_t)RS*XS*2*8, stream);  // all 8 X arrays contiguous
  fill_col<<<(RS+255)/256, 256, 0, stream>>>(XaRH, XaRL, XaCH, XaCL, 0, x, (long long)TTNN);

  dim3 fgrid(NB, 8);
  for (int t = 0; t < TT; ++t) {
    fused_half<1,0,1><<<fgrid, 512, 0, stream>>>(
        AsH, AsL, As2H, As2L, 0,
        XaRH, XaRL, XaCH, XaCL, XbRH, XbRL, XbCH, XbCL,
        WgeH, WgeL, egb, h, rb, nullptr, nullptr, nullptr, t,
        nullptr, nullptr, 1, 0, 1);
    fused_half<0,0,1><<<fgrid, 512, 0, stream>>>(
        AsH, AsL, As2H, As2L, 0,
        XbRH, XbRL, XbCH, XbCL, XaRH, XaRL, XaCH, XaCL,
        WueH, WueL, eub, h, rb, nullptr, nullptr, nullptr, t,
        (t < TT-1 ? x + (size_t)(t+1)*NN : nullptr),
        (t < TT-1 ? nullptr : ycov),
        1, (t < TT-1 ? 1 : 2), 1);
  }

  edyn_k<<<RS/4, 256, 0, stream>>>(h, ne, hW, hb, Ed);
  softmax_graph<<<NB*64, 512, 0, stream>>>(Ed, (long long)NN*EE, AdH, AdL, (long long)NN*NN);
  sq_mm<<<dim3(8,8,NB), 256, 0, stream>>>(AdH, AdL, (long long)NN*NN, Ad2H, nullptr, (long long)NN*NN);

  for (int t = 0; t < TT; ++t) {
    fused_half<1,0,0><<<fgrid, 512, 0, stream>>>(
        AdH, nullptr, Ad2H, nullptr, (long long)NN*NN,
        XaRH, XaRL, XaCH, XaCL, XbRH, XbRL, XbCH, XbCL,
        WgdH, WgdL, dgb, h, rb, nullptr, nullptr, nullptr, t,
        nullptr, nullptr, 2, 0, 1);
    fused_half<0,1,0><<<fgrid, 512, 0, stream>>>(
        AdH, nullptr, Ad2H, nullptr, (long long)NN*NN,
        XbRH, XbRL, XbCH, XbCL, XaRH, XaRL, XaCH, XaCL,
        WudH, WudL, dub, h, rb, pW, pb, out, t,
        nullptr, (t < TT-1 ? ycov + (size_t)(t+1)*NN : nullptr),
        2, 2, (t < TT-1 ? 1 : 0));
  }
}

// Round 18
// 1558.980 us; speedup vs baseline: 2.1369x; 1.0372x over previous
//
#include <hip/hip_runtime.h>

#define NB 32
#define TT 12
#define NN 512
#define HH 64
#define EE 10
#define XS 80       // X row width (halves)
#define KD 240      // dense K = 3*80
#define RS (NB*NN)  // 16384 global rows
#define TTNN (TT*NN)
#define GP 164

typedef _Float16 f16;
typedef __attribute__((ext_vector_type(4))) _Float16 f16x4;
typedef __attribute__((ext_vector_type(8))) _Float16 f16x8;
typedef __attribute__((ext_vector_type(4))) float f32x4;

#define MFMA32(a,bb,c) __builtin_amdgcn_mfma_f32_16x16x32_f16(a,bb,c,0,0,0)
#define MFMA16(a,bb,c) __builtin_amdgcn_mfma_f32_16x16x16f16(a,bb,c,0,0,0)

__device__ __forceinline__ void barrier_lgkm() {
  asm volatile("s_waitcnt lgkmcnt(0)" ::: "memory");
  __builtin_amdgcn_s_barrier();
  __builtin_amdgcn_sched_barrier(0);
}

union SMem {
  struct {
    f16 PsH[2][2][64][32], PsL[2][2][64][32];  // [buf][A=0/A2=1][row][k]
    f16 XtH[2][80][40], XtL[2][80][40];        // [buf][col][k]
  } s1;
  struct {
    f16 gH[64][GP], gL[64][GP];                // [row][g1|g2]
  } s2;
};

// ---------------- fold Chebyshev into weights; transpose to [O][KD]; f16 split ----
__global__ void fold_w_t(const float* __restrict__ src, f16* __restrict__ WtH,
                         f16* __restrict__ WtL, int C, int O){
  int idx = blockIdx.x*256 + threadIdx.x;
  if (idx >= O*KD) return;
  int o = idx / KD;
  int k = idx % KD;
  int s = k / XS, c = k % XS;
  float v = 0.f;
  if (c < C) {
    if (s == 0)      v = src[c*O+o] - src[(2*C+c)*O+o];
    else if (s == 1) v = src[(C+c)*O+o];
    else             v = 2.f*src[(2*C+c)*O+o];
  }
  f16 hi = (f16)v;
  WtH[idx] = hi;
  WtL[idx] = (f16)(v - (float)hi);
}

// ---------------- A = softmax(relu(E E^T)): 8 rows/block, wave-per-row ----------
__global__ __launch_bounds__(512) void softmax_graph(
    const float* __restrict__ Emb, long long ebs,
    f16* __restrict__ AH, f16* __restrict__ AL, long long abs_)
{
  __shared__ float Es[NN*EE];
  int b  = blockIdx.x >> 6;
  int rt = blockIdx.x & 63;
  const float* Eb = Emb + (long long)b*ebs;
  int tid = threadIdx.x;
  for (int i = tid; i < NN*EE; i += 512) Es[i] = Eb[i];
  __syncthreads();
  int wave = tid >> 6, lane = tid & 63;
  int r = rt*8 + wave;
  float q[EE];
  #pragma unroll
  for (int e = 0; e < EE; ++e) q[e] = Es[r*EE + e];
  float sv[8];
  float mx = 0.f;
  #pragma unroll
  for (int j = 0; j < 8; ++j) {
    int m = 64*j + lane;
    float s = 0.f;
    #pragma unroll
    for (int e = 0; e < EE; ++e) s += q[e]*Es[m*EE + e];
    s = fmaxf(s, 0.f);
    sv[j] = s;
    mx = fmaxf(mx, s);
  }
  #pragma unroll
  for (int off = 32; off >= 1; off >>= 1) mx = fmaxf(mx, __shfl_xor(mx, off, 64));
  float sm = 0.f;
  #pragma unroll
  for (int j = 0; j < 8; ++j) { sv[j] = expf(sv[j] - mx); sm += sv[j]; }
  #pragma unroll
  for (int off = 32; off >= 1; off >>= 1) sm += __shfl_xor(sm, off, 64);
  float inv = 1.f / sm;
  #pragma unroll
  for (int j = 0; j < 8; ++j) {
    int m = 64*j + lane;
    float p = sv[j] * inv;
    long long o = (long long)b*abs_ + (long long)r*NN + m;
    f16 hi = (f16)p;
    AH[o] = hi;
    AL[o] = (f16)(p - (float)hi);
  }
}

// ---------------- B = A @ A ~= (A_h+A_l)·A_h ; H-only output ---------------------
__global__ __launch_bounds__(256) void sq_mm(
    const f16* __restrict__ AH, const f16* __restrict__ AL, long long astr,
    f16* __restrict__ BH, long long bstr)
{
  __shared__ f16 RsH[64][36], RsL[64][36], CsH[64][34];
  int b = blockIdx.z;
  int rows0 = blockIdx.y*64, cols0 = blockIdx.x*64;
  const f16* Ah = AH + (long long)b*astr;
  const f16* Al = AL + (long long)b*astr;
  int tid = threadIdx.x, l = tid & 63, w = tid >> 6, lr = l & 15, lg = l >> 4;
  int ar = w*16 + lr;
  int st_row = tid >> 2, st_seg = tid & 3;
  int sx_m = tid >> 3, sx_sub = tid & 7;
  f32x4 acc[4] = {};
  for (int kt = 0; kt < 16; ++kt) {
    int k0 = kt*32;
    barrier_lgkm();
    {
      f16x8 vh = *(const f16x8*)&Ah[(long long)(rows0+st_row)*NN + k0 + 8*st_seg];
      f16x8 vl = *(const f16x8*)&Al[(long long)(rows0+st_row)*NN + k0 + 8*st_seg];
      *(f16x8*)&RsH[st_row][8*st_seg] = vh;
      *(f16x8*)&RsL[st_row][8*st_seg] = vl;
    }
    #pragma unroll
    for (int j = 0; j < 2; ++j) {
      int c4 = sx_sub + 8*j;   // 0..15
      f16x4 vh = *(const f16x4*)&Ah[(long long)(k0+sx_m)*NN + cols0 + 4*c4];
      #pragma unroll
      for (int q = 0; q < 4; ++q)
        CsH[4*c4+q][sx_m] = vh[q];
    }
    barrier_lgkm();
    f16x8 a_h = *(const f16x8*)&RsH[ar][8*lg];
    f16x8 a_l = *(const f16x8*)&RsL[ar][8*lg];
    #pragma unroll
    for (int cf = 0; cf < 4; ++cf) {
      int c = cf*16 + lr;
      f16x8 b_h = *(const f16x8*)&CsH[c][8*lg];
      acc[cf] = MFMA32(a_h, b_h, acc[cf]);
      acc[cf] = MFMA32(a_l, b_h, acc[cf]);
    }
  }
  #pragma unroll
  for (int cf = 0; cf < 4; ++cf) {
    #pragma unroll
    for (int reg = 0; reg < 4; ++reg) {
      int r = rows0 + w*16 + lg*4 + reg;
      int c = cols0 + cf*16 + lr;
      long long o = (long long)b*bstr + (long long)r*NN + c;
      BH[o] = (f16)acc[cf][reg];
    }
  }
}

// ---------------- write one special column of X (dual layout, split) -------------
__global__ void fill_col(f16* __restrict__ XRH, f16* __restrict__ XRL,
                         f16* __restrict__ XCH, f16* __restrict__ XCL, int col,
                         const float* __restrict__ src, long long sstr){
  int row = blockIdx.x*256 + threadIdx.x;
  if (row >= RS) return;
  float v = src[(long long)(row>>9)*sstr + (row & 511)];
  f16 hi = (f16)v;
  f16 lo = (f16)(v - (float)hi);
  XRH[(long long)row*XS + col] = hi;
  XRL[(long long)row*XS + col] = lo;
  XCH[(long long)col*RS + row] = hi;
  XCL[(long long)col*RS + row] = lo;
}

// ---------------- fused half-step; SPLITA: A stored/used as f16 H+L vs H only ---
template<int GATE, int DEC, int SPLITA>
__global__ __launch_bounds__(512, 2) void fused_half(
    const f16* __restrict__ AH, const f16* __restrict__ AL,
    const f16* __restrict__ A2H, const f16* __restrict__ A2L, long long astr,
    const f16* __restrict__ XiRH, const f16* __restrict__ XiRL,
    const f16* __restrict__ XiCH, const f16* __restrict__ XiCL,
    f16* __restrict__ XoRH, f16* __restrict__ XoRL,
    f16* __restrict__ XoCH, f16* __restrict__ XoCL,
    const f16* __restrict__ WH, const f16* __restrict__ WL,
    const float* __restrict__ bias,
    float* __restrict__ hbuf, float* __restrict__ rb,
    const float* __restrict__ pWv, const float* __restrict__ pbv,
    float* __restrict__ outp, int t,
    const float* __restrict__ s0src, const float* __restrict__ s1src,
    int ns, int ns_next, int writeX)
{
  __shared__ SMem sm;
  __shared__ float gpart[64];
  const int b = blockIdx.x;
  const int rows0 = blockIdx.y * 64;
  const long long bNN = (long long)b*NN;
  const int tid = threadIdx.x;
  const int w = tid >> 6, l = tid & 63;
  const int lr = l & 15, lg = l >> 4;
  const int grp = w >> 2;
  const int w4 = w & 3;
  const int ar = w4*16 + lr;
  const int asw = (ar >> 2) & 3;

  // A/A2 staging mapping: tid<256 stages A, tid>=256 stages A2
  const int stw = (tid < 256) ? 0 : 1;
  const int at = tid & 255;
  const int st_row = at >> 2, st_seg = at & 3;
  const int a_sw = (st_row >> 2) & 3;
  const f16* PgH = (stw ? A2H : AH) + (long long)b*astr + (long long)rows0*NN;
  const f16* PgL = SPLITA ? ((stw ? A2L : AL) + (long long)b*astr + (long long)rows0*NN)
                          : nullptr;

  // X staging mapping (col-major source)
  const int xc = tid >> 3;
  const int xsub = tid & 7;
  const int xa = xsub >> 2;
  const int xo = xsub & 3;
  const int xc2 = (tid < 128) ? (64 + xc) : 64;
  const f16* XC1 = (xa ? XiCL : XiCH) + (long long)xc*RS + bNN;
  const f16* XC2 = (xa ? XiCL : XiCH) + (long long)xc2*RS + bNN;

  f16x8 rH0{}, rL0{}, x10{}, x20{}, rH1{}, rL1{}, x11{}, x21{};

  auto LOAD = [&](int kt, f16x8& rH, f16x8& rL, f16x8& x1, f16x8& x2){
    int k0 = kt*32;
    long long ao = (long long)st_row*NN + k0 + 8*st_seg;
    rH = *(const f16x8*)&PgH[ao];
    if constexpr (SPLITA) rL = *(const f16x8*)&PgL[ao];
    x1 = *(const f16x8*)&XC1[k0 + 8*xo];
    if (tid < 128) x2 = *(const f16x8*)&XC2[k0 + 8*xo];
  };
  auto STORE = [&](int buf, f16x8& rH, f16x8& rL, f16x8& x1, f16x8& x2){
    int sc = 8*(st_seg ^ a_sw);
    *(f16x8*)&sm.s1.PsH[buf][stw][st_row][sc] = rH;
    if constexpr (SPLITA) *(f16x8*)&sm.s1.PsL[buf][stw][st_row][sc] = rL;
    f16 (*xt)[40] = xa ? sm.s1.XtL[buf] : sm.s1.XtH[buf];
    *(f16x8*)&xt[xc][8*xo] = x1;
    if (tid < 128) *(f16x8*)&xt[64 + xc][8*xo] = x2;
  };
  f32x4 acc[5] = {};
  auto COMP = [&](int buf){
    int sa = 8*(lg ^ asw);
    f16x8 ah = *(const f16x8*)&sm.s1.PsH[buf][grp][ar][sa];
    f16x8 al2{};
    if constexpr (SPLITA) al2 = *(const f16x8*)&sm.s1.PsL[buf][grp][ar][sa];
    __builtin_amdgcn_s_setprio(1);
    #pragma unroll
    for (int cf = 0; cf < 5; ++cf) {
      int c = cf*16 + lr;
      f16x8 bh = *(const f16x8*)&sm.s1.XtH[buf][c][8*lg];
      f16x8 bl = *(const f16x8*)&sm.s1.XtL[buf][c][8*lg];
      acc[cf] = MFMA32(ah, bh, acc[cf]);
      acc[cf] = MFMA32(ah, bl, acc[cf]);
      if constexpr (SPLITA) acc[cf] = MFMA32(al2, bh, acc[cf]);
    }
    __builtin_amdgcn_s_setprio(0);
  };

  LOAD(0, rH0,rL0,x10,x20);
  LOAD(1, rH1,rL1,x11,x21);
  STORE(0, rH0,rL0,x10,x20);
  barrier_lgkm();
  #pragma unroll
  for (int kt2 = 0; kt2 < 8; ++kt2) {
    int kt = kt2*2;
    if (kt+2 < 16) LOAD(kt+2, rH0,rL0,x10,x20);
    COMP(0);
    STORE(1, rH1,rL1,x11,x21);
    barrier_lgkm();
    if (kt+3 < 16) LOAD(kt+3, rH1,rL1,x11,x21);
    COMP(1);
    if (kt+2 < 16) STORE(0, rH0,rL0,x10,x20);
    barrier_lgkm();
  }

  // ---- dump g (split) into LDS union (staging dead after final barrier) ----
  {
    int go_ = grp*80;
    #pragma unroll
    for (int cf = 0; cf < 5; ++cf) {
      int col = go_ + cf*16 + lr;
      #pragma unroll
      for (int reg = 0; reg < 4; ++reg) {
        int row = w4*16 + lg*4 + reg;
        float v = acc[cf][reg];
        f16 hi = (f16)v;
        sm.s2.gH[row][col] = hi;
        sm.s2.gL[row][col] = (f16)(v - (float)hi);
      }
    }
  }
  barrier_lgkm();

  // ---- dense: K = [x(rm global) | g1(LDS) | g2(LDS)], W from global ----
  constexpr int CFW = GATE ? 4 : 2;
  f32x4 accD[CFW] = {};
  const long long grow0 = bNN + rows0 + w4*16;
  const f16* xrH = XiRH + (grow0 + lr)*XS;
  const f16* xrL = XiRL + (grow0 + lr)*XS;
  #pragma unroll
  for (int c = 0; c < 15; ++c) {
    f16x4 a_h, a_l;
    if (c < 5) {
      a_h = *(const f16x4*)&xrH[c*16 + 4*lg];
      a_l = *(const f16x4*)&xrL[c*16 + 4*lg];
    } else {
      int gk = (c-5)*16 + 4*lg;
      a_h = *(const f16x4*)&sm.s2.gH[w4*16 + lr][gk];
      a_l = *(const f16x4*)&sm.s2.gL[w4*16 + lr][gk];
    }
    #pragma unroll
    for (int cf = 0; cf < CFW; ++cf) {
      int o = grp*(CFW*16) + cf*16 + lr;
      f16x4 b_h = *(const f16x4*)&WH[(long long)o*KD + c*16 + 4*lg];
      f16x4 b_l = *(const f16x4*)&WL[(long long)o*KD + c*16 + 4*lg];
      accD[cf] = MFMA16(a_h, b_h, accD[cf]);
      accD[cf] = MFMA16(a_h, b_l, accD[cf]);
      accD[cf] = MFMA16(a_l, b_h, accD[cf]);
    }
  }

  // ---- epilogue ----
  if constexpr (GATE) {
    #pragma unroll
    for (int cf = 0; cf < CFW; ++cf) {
      int o = grp*64 + cf*16 + lr;
      float bi = bias[o];
      #pragma unroll
      for (int reg = 0; reg < 4; ++reg) {
        long long grow = grow0 + lg*4 + reg;
        float v = 1.f/(1.f + expf(-(accD[cf][reg] + bi)));
        if (grp == 0) {
          float zh = v * hbuf[grow*HH + o];
          f16 hi = (f16)zh; f16 lo = (f16)(zh - (float)hi);
          XoRH[grow*XS + ns + o] = hi; XoRL[grow*XS + ns + o] = lo;
          XoCH[(long long)(ns+o)*RS + grow] = hi; XoCL[(long long)(ns+o)*RS + grow] = lo;
        } else {
          rb[grow*HH + (o - HH)] = v;
        }
      }
    }
    if (grp == 0 && lr < ns) {
      #pragma unroll
      for (int reg = 0; reg < 4; ++reg) {
        long long grow = grow0 + lg*4 + reg;
        f16 vh = XiRH[grow*XS + lr], vl = XiRL[grow*XS + lr];
        XoRH[grow*XS + lr] = vh; XoRL[grow*XS + lr] = vl;
        XoCH[(long long)lr*RS + grow] = vh; XoCL[(long long)lr*RS + grow] = vl;
      }
    }
  } else {
    float gop[4] = {0.f,0.f,0.f,0.f};
    #pragma unroll
    for (int cf = 0; cf < CFW; ++cf) {
      int o = grp*32 + cf*16 + lr;
      float bi = bias[o];
      float pwv = 0.f;
      if constexpr (DEC) pwv = pWv[o];
      #pragma unroll
      for (int reg = 0; reg < 4; ++reg) {
        long long grow = grow0 + lg*4 + reg;
        float hc = tanhf(accD[cf][reg] + bi);
        float rv = rb[grow*HH + o];
        float hv = hbuf[grow*HH + o];
        float hn = rv*hv + (1.f - rv)*hc;
        hbuf[grow*HH + o] = hn;
        if (writeX) {
          f16 hi = (f16)hn; f16 lo = (f16)(hn - (float)hi);
          XoRH[grow*XS + ns_next + o] = hi; XoRL[grow*XS + ns_next + o] = lo;
          XoCH[(long long)(ns_next+o)*RS + grow] = hi; XoCL[(long long)(ns_next+o)*RS + grow] = lo;
        }
        if constexpr (DEC) gop[reg] += hn * pwv;
      }
    }
    if constexpr (DEC) {
      #pragma unroll
      for (int reg = 0; reg < 4; ++reg) {
        #pragma unroll
        for (int off = 8; off >= 1; off >>= 1)
          gop[reg] += __shfl_xor(gop[reg], off, 64);
      }
      if (grp == 1 && lr == 0) {
        #pragma unroll
        for (int reg = 0; reg < 4; ++reg)
          gpart[w4*16 + lg*4 + reg] = gop[reg];
      }
      barrier_lgkm();
      if (grp == 0 && lr == 0) {
        float pb0 = pbv[0];
        #pragma unroll
        for (int reg = 0; reg < 4; ++reg) {
          int n = rows0 + w4*16 + lg*4 + reg;
          long long grow = bNN + n;
          float go = gop[reg] + gpart[w4*16 + lg*4 + reg] + pb0;
          outp[((long long)b*TT + t)*NN + n] = go;
          if (writeX) {
            f16 hi = (f16)go; f16 lo = (f16)(go - (float)hi);
            XoRH[grow*XS] = hi; XoRL[grow*XS] = lo;
            XoCH[grow] = hi; XoCL[grow] = lo;
            float yv = s1src[(long long)b*TTNN + n];
            f16 hy = (f16)yv; f16 ly = (f16)(yv - (float)hy);
            XoRH[grow*XS + 1] = hy; XoRL[grow*XS + 1] = ly;
            XoCH[RS + grow] = hy; XoCL[RS + grow] = ly;
          }
        }
      }
    } else {
      if (writeX && grp == 0 && lr == 0) {
        #pragma unroll
        for (int reg = 0; reg < 4; ++reg) {
          int n = rows0 + w4*16 + lg*4 + reg;
          long long grow = bNN + n;
          float v0 = s0src ? s0src[(long long)b*TTNN + n] : 0.f;
          f16 h0 = (f16)v0; f16 l0 = (f16)(v0 - (float)h0);
          XoRH[grow*XS] = h0; XoRL[grow*XS] = l0;
          XoCH[grow] = h0; XoCL[grow] = l0;
          if (ns_next == 2 && s1src) {
            float v1 = s1src[(long long)b*TTNN + n];
            f16 h1 = (f16)v1; f16 l1 = (f16)(v1 - (float)h1);
            XoRH[grow*XS + 1] = h1; XoRL[grow*XS + 1] = l1;
            XoCH[RS + grow] = h1; XoCL[RS + grow] = l1;
          }
        }
      }
    }
  }
}

// ---------------- E_dyn = ne + h @ hyper_W + hyper_b -----------------------------
__global__ __launch_bounds__(256) void edyn_k(
    const float* __restrict__ h, const float* __restrict__ ne,
    const float* __restrict__ hW, const float* __restrict__ hb, float* __restrict__ Ed)
{
  int row = blockIdx.x*4 + (threadIdx.x >> 6);
  int lane = threadIdx.x & 63;
  float hv = h[(long long)row*HH + lane];
  float myval = 0.f;
  #pragma unroll
  for (int e = 0; e < EE; ++e) {
    float v = hv * hW[lane*EE + e];
    #pragma unroll
    for (int off = 32; off >= 1; off >>= 1) v += __shfl_xor(v, off, 64);
    if (lane == e) myval = v;
  }
  if (lane < EE) {
    int n = row & 511;
    Ed[(long long)row*EE + lane] = ne[n*EE + lane] + hb[lane] + myval;
  }
}

extern "C" void kernel_launch(void* const* d_in, const int* in_sizes, int n_in,
                              void* d_out, int out_size, void* d_ws, size_t ws_size,
                              hipStream_t stream)
{
  const float* x    = (const float*)d_in[0];
  const float* ycov = (const float*)d_in[1];
  const float* ne   = (const float*)d_in[2];
  const float* egW  = (const float*)d_in[3];
  const float* egb  = (const float*)d_in[4];
  const float* euW  = (const float*)d_in[5];
  const float* eub  = (const float*)d_in[6];
  const float* dgW  = (const float*)d_in[7];
  const float* dgb  = (const float*)d_in[8];
  const float* duW  = (const float*)d_in[9];
  const float* dub  = (const float*)d_in[10];
  const float* pW   = (const float*)d_in[11];
  const float* pb   = (const float*)d_in[12];
  const float* hW   = (const float*)d_in[13];
  const float* hb   = (const float*)d_in[14];
  float* out = (float*)d_out;

  char* p = (char*)d_ws;
  f16* AsH  = (f16*)p; p += (size_t)NN*NN*2;
  f16* AsL  = (f16*)p; p += (size_t)NN*NN*2;
  f16* As2H = (f16*)p; p += (size_t)NN*NN*2;
  f16* AdH  = (f16*)p; p += (size_t)NB*NN*NN*2;
  f16* AdL  = (f16*)p; p += (size_t)NB*NN*NN*2;
  f16* Ad2H = (f16*)p; p += (size_t)NB*NN*NN*2;
  f16* XaRH = (f16*)p; p += (size_t)RS*XS*2;
  f16* XaRL = (f16*)p; p += (size_t)RS*XS*2;
  f16* XaCH = (f16*)p; p += (size_t)RS*XS*2;
  f16* XaCL = (f16*)p; p += (size_t)RS*XS*2;
  f16* XbRH = (f16*)p; p += (size_t)RS*XS*2;
  f16* XbRL = (f16*)p; p += (size_t)RS*XS*2;
  f16* XbCH = (f16*)p; p += (size_t)RS*XS*2;
  f16* XbCL = (f16*)p; p += (size_t)RS*XS*2;
  float* h  = (float*)p; p += (size_t)RS*HH*4;
  float* rb = (float*)p; p += (size_t)RS*HH*4;
  float* Ed = (float*)p; p += (size_t)RS*EE*4;
  f16* WgeH = (f16*)p; p += (size_t)128*KD*2;
  f16* WgeL = (f16*)p; p += (size_t)128*KD*2;
  f16* WueH = (f16*)p; p += (size_t)64*KD*2;
  f16* WueL = (f16*)p; p += (size_t)64*KD*2;
  f16* WgdH = (f16*)p; p += (size_t)128*KD*2;
  f16* WgdL = (f16*)p; p += (size_t)128*KD*2;
  f16* WudH = (f16*)p; p += (size_t)64*KD*2;
  f16* WudL = (f16*)p; p += (size_t)64*KD*2;

  fold_w_t<<<(128*KD+255)/256, 256, 0, stream>>>(egW, WgeH, WgeL, 65, 128);
  fold_w_t<<<(64*KD +255)/256, 256, 0, stream>>>(euW, WueH, WueL, 65, 64);
  fold_w_t<<<(128*KD+255)/256, 256, 0, stream>>>(dgW, WgdH, WgdL, 66, 128);
  fold_w_t<<<(64*KD +255)/256, 256, 0, stream>>>(duW, WudH, WudL, 66, 64);

  softmax_graph<<<64, 512, 0, stream>>>(ne, 0, AsH, AsL, 0);
  sq_mm<<<dim3(8,8,1), 256, 0, stream>>>(AsH, AsL, 0, As2H, 0);
  (void)hipMemsetAsync(h, 0, (size_t)RS*HH*4, stream);
  (void)hipMemsetAsync(XaRH, 0, (size_t)RS*XS*2*8, stream);  // all 8 X arrays contiguous
  fill_col<<<(RS+255)/256, 256, 0, stream>>>(XaRH, XaRL, XaCH, XaCL, 0, x, (long long)TTNN);

  dim3 fgrid(NB, 8);
  for (int t = 0; t < TT; ++t) {
    fused_half<1,0,0><<<fgrid, 512, 0, stream>>>(
        AsH, nullptr, As2H, nullptr, 0,
        XaRH, XaRL, XaCH, XaCL, XbRH, XbRL, XbCH, XbCL,
        WgeH, WgeL, egb, h, rb, nullptr, nullptr, nullptr, t,
        nullptr, nullptr, 1, 0, 1);
    fused_half<0,0,0><<<fgrid, 512, 0, stream>>>(
        AsH, nullptr, As2H, nullptr, 0,
        XbRH, XbRL, XbCH, XbCL, XaRH, XaRL, XaCH, XaCL,
        WueH, WueL, eub, h, rb, nullptr, nullptr, nullptr, t,
        (t < TT-1 ? x + (size_t)(t+1)*NN : nullptr),
        (t < TT-1 ? nullptr : ycov),
        1, (t < TT-1 ? 1 : 2), 1);
  }

  edyn_k<<<RS/4, 256, 0, stream>>>(h, ne, hW, hb, Ed);
  softmax_graph<<<NB*64, 512, 0, stream>>>(Ed, (long long)NN*EE, AdH, AdL, (long long)NN*NN);
  sq_mm<<<dim3(8,8,NB), 256, 0, stream>>>(AdH, AdL, (long long)NN*NN, Ad2H, (long long)NN*NN);

  for (int t = 0; t < TT; ++t) {
    fused_half<1,0,0><<<fgrid, 512, 0, stream>>>(
        AdH, nullptr, Ad2H, nullptr, (long long)NN*NN,
        XaRH, XaRL, XaCH, XaCL, XbRH, XbRL, XbCH, XbCL,
        WgdH, WgdL, dgb, h, rb, nullptr, nullptr, nullptr, t,
        nullptr, nullptr, 2, 0, 1);
    fused_half<0,1,0><<<fgrid, 512, 0, stream>>>(
        AdH, nullptr, Ad2H, nullptr, (long long)NN*NN,
        XbRH, XbRL, XbCH, XbCL, XaRH, XaRL, XaCH, XaCL,
        WudH, WudL, dub, h, rb, pW, pb, out, t,
        nullptr, (t < TT-1 ? ycov + (size_t)(t+1)*NN : nullptr),
        2, 2, (t < TT-1 ? 1 : 0));
  }
}

// Round 19
// 1292.170 us; speedup vs baseline: 2.5781x; 1.2065x over previous
//
#include <hip/hip_runtime.h>

#define NB 32
#define TT 12
#define NN 512
#define HH 64
#define EE 10
#define XS 80       // X row width (halves)
#define KD 240      // dense K = 3*80
#define RS (NB*NN)  // 16384 global rows
#define TTNN (TT*NN)
#define GP 164

typedef _Float16 f16;
typedef __attribute__((ext_vector_type(4))) _Float16 f16x4;
typedef __attribute__((ext_vector_type(8))) _Float16 f16x8;
typedef __attribute__((ext_vector_type(4))) float f32x4;

#define MFMA32(a,bb,c) __builtin_amdgcn_mfma_f32_16x16x32_f16(a,bb,c,0,0,0)
#define MFMA16(a,bb,c) __builtin_amdgcn_mfma_f32_16x16x16f16(a,bb,c,0,0,0)

__device__ __forceinline__ void barrier_lgkm() {
  asm volatile("s_waitcnt lgkmcnt(0)" ::: "memory");
  __builtin_amdgcn_s_barrier();
  __builtin_amdgcn_sched_barrier(0);
}

union SMem {
  struct {
    f16 PsH[2][2][64][32];        // [buf][A=0/A2=1][row][k]  16 KB
    f16 XtH[2][80][40];           // [buf][col][k]            12.8 KB
  } s1;
  struct {
    f16 gH[64][GP], gL[64][GP];   // [row][g1|g2]             42 KB
  } s2;
};

// ---------------- fold Chebyshev into weights; transpose to [O][KD]; f16 split ----
__global__ void fold_w_t(const float* __restrict__ src, f16* __restrict__ WtH,
                         f16* __restrict__ WtL, int C, int O){
  int idx = blockIdx.x*256 + threadIdx.x;
  if (idx >= O*KD) return;
  int o = idx / KD;
  int k = idx % KD;
  int s = k / XS, c = k % XS;
  float v = 0.f;
  if (c < C) {
    if (s == 0)      v = src[c*O+o] - src[(2*C+c)*O+o];
    else if (s == 1) v = src[(C+c)*O+o];
    else             v = 2.f*src[(2*C+c)*O+o];
  }
  f16 hi = (f16)v;
  WtH[idx] = hi;
  WtL[idx] = (f16)(v - (float)hi);
}

// ---------------- A = softmax(relu(E E^T)): 8 rows/block, wave-per-row ----------
__global__ __launch_bounds__(512) void softmax_graph(
    const float* __restrict__ Emb, long long ebs,
    f16* __restrict__ AH, f16* __restrict__ AL, long long abs_)
{
  __shared__ float Es[NN*EE];
  int b  = blockIdx.x >> 6;
  int rt = blockIdx.x & 63;
  const float* Eb = Emb + (long long)b*ebs;
  int tid = threadIdx.x;
  for (int i = tid; i < NN*EE; i += 512) Es[i] = Eb[i];
  __syncthreads();
  int wave = tid >> 6, lane = tid & 63;
  int r = rt*8 + wave;
  float q[EE];
  #pragma unroll
  for (int e = 0; e < EE; ++e) q[e] = Es[r*EE + e];
  float sv[8];
  float mx = 0.f;
  #pragma unroll
  for (int j = 0; j < 8; ++j) {
    int m = 64*j + lane;
    float s = 0.f;
    #pragma unroll
    for (int e = 0; e < EE; ++e) s += q[e]*Es[m*EE + e];
    s = fmaxf(s, 0.f);
    sv[j] = s;
    mx = fmaxf(mx, s);
  }
  #pragma unroll
  for (int off = 32; off >= 1; off >>= 1) mx = fmaxf(mx, __shfl_xor(mx, off, 64));
  float sm = 0.f;
  #pragma unroll
  for (int j = 0; j < 8; ++j) { sv[j] = expf(sv[j] - mx); sm += sv[j]; }
  #pragma unroll
  for (int off = 32; off >= 1; off >>= 1) sm += __shfl_xor(sm, off, 64);
  float inv = 1.f / sm;
  #pragma unroll
  for (int j = 0; j < 8; ++j) {
    int m = 64*j + lane;
    float p = sv[j] * inv;
    long long o = (long long)b*abs_ + (long long)r*NN + m;
    f16 hi = (f16)p;
    AH[o] = hi;
    AL[o] = (f16)(p - (float)hi);
  }
}

// ---------------- B = A @ A ~= (A_h+A_l)·A_h ; H-only output ---------------------
__global__ __launch_bounds__(256) void sq_mm(
    const f16* __restrict__ AH, const f16* __restrict__ AL, long long astr,
    f16* __restrict__ BH, long long bstr)
{
  __shared__ f16 RsH[64][36], RsL[64][36], CsH[64][34];
  int b = blockIdx.z;
  int rows0 = blockIdx.y*64, cols0 = blockIdx.x*64;
  const f16* Ah = AH + (long long)b*astr;
  const f16* Al = AL + (long long)b*astr;
  int tid = threadIdx.x, l = tid & 63, w = tid >> 6, lr = l & 15, lg = l >> 4;
  int ar = w*16 + lr;
  int st_row = tid >> 2, st_seg = tid & 3;
  int sx_m = tid >> 3, sx_sub = tid & 7;
  f32x4 acc[4] = {};
  for (int kt = 0; kt < 16; ++kt) {
    int k0 = kt*32;
    barrier_lgkm();
    {
      f16x8 vh = *(const f16x8*)&Ah[(long long)(rows0+st_row)*NN + k0 + 8*st_seg];
      f16x8 vl = *(const f16x8*)&Al[(long long)(rows0+st_row)*NN + k0 + 8*st_seg];
      *(f16x8*)&RsH[st_row][8*st_seg] = vh;
      *(f16x8*)&RsL[st_row][8*st_seg] = vl;
    }
    #pragma unroll
    for (int j = 0; j < 2; ++j) {
      int c4 = sx_sub + 8*j;   // 0..15
      f16x4 vh = *(const f16x4*)&Ah[(long long)(k0+sx_m)*NN + cols0 + 4*c4];
      #pragma unroll
      for (int q = 0; q < 4; ++q)
        CsH[4*c4+q][sx_m] = vh[q];
    }
    barrier_lgkm();
    f16x8 a_h = *(const f16x8*)&RsH[ar][8*lg];
    f16x8 a_l = *(const f16x8*)&RsL[ar][8*lg];
    #pragma unroll
    for (int cf = 0; cf < 4; ++cf) {
      int c = cf*16 + lr;
      f16x8 b_h = *(const f16x8*)&CsH[c][8*lg];
      acc[cf] = MFMA32(a_h, b_h, acc[cf]);
      acc[cf] = MFMA32(a_l, b_h, acc[cf]);
    }
  }
  #pragma unroll
  for (int cf = 0; cf < 4; ++cf) {
    #pragma unroll
    for (int reg = 0; reg < 4; ++reg) {
      int r = rows0 + w*16 + lg*4 + reg;
      int c = cols0 + cf*16 + lr;
      long long o = (long long)b*bstr + (long long)r*NN + c;
      BH[o] = (f16)acc[cf][reg];
    }
  }
}

// ---------------- write one special column of X (dual layout, single f16) --------
__global__ void fill_col(f16* __restrict__ XRH, f16* __restrict__ XCH, int col,
                         const float* __restrict__ src, long long sstr){
  int row = blockIdx.x*256 + threadIdx.x;
  if (row >= RS) return;
  float v = src[(long long)(row>>9)*sstr + (row & 511)];
  f16 hi = (f16)v;
  XRH[(long long)row*XS + col] = hi;
  XCH[(long long)col*RS + row] = hi;
}

// ---------------- fused half-step: single-f16 A and X ----------------------------
template<int GATE, int DEC>
__global__ __launch_bounds__(512, 2) void fused_half(
    const f16* __restrict__ AH, const f16* __restrict__ A2H, long long astr,
    const f16* __restrict__ XiRH, const f16* __restrict__ XiCH,
    f16* __restrict__ XoRH, f16* __restrict__ XoCH,
    const f16* __restrict__ WH, const f16* __restrict__ WL,
    const float* __restrict__ bias,
    float* __restrict__ hbuf, float* __restrict__ rb,
    const float* __restrict__ pWv, const float* __restrict__ pbv,
    float* __restrict__ outp, int t,
    const float* __restrict__ s0src, const float* __restrict__ s1src,
    int ns, int ns_next, int writeX)
{
  __shared__ SMem sm;
  __shared__ float gpart[64];
  const int b = blockIdx.x;
  const int rows0 = blockIdx.y * 64;
  const long long bNN = (long long)b*NN;
  const int tid = threadIdx.x;
  const int w = tid >> 6, l = tid & 63;
  const int lr = l & 15, lg = l >> 4;
  const int grp = w >> 2;
  const int w4 = w & 3;
  const int ar = w4*16 + lr;
  const int asw = (ar >> 2) & 3;

  // A/A2 staging mapping: tid<256 stages A-H, tid>=256 stages A2-H
  const int stw = (tid < 256) ? 0 : 1;
  const int at = tid & 255;
  const int st_row = at >> 2, st_seg = at & 3;
  const int a_sw = (st_row >> 2) & 3;
  const f16* PgH = (stw ? A2H : AH) + (long long)b*astr + (long long)rows0*NN;

  // X staging (col-major source, H only): tid<320 covers 80 cols x 4 chunks
  const int xc = tid >> 2;         // 0..127 (valid < 80)
  const int xo = tid & 3;
  const int xok = (xc < 80);
  const f16* XC1 = XiCH + (long long)(xok ? xc : 0)*RS + bNN;

  f16x8 rH0{}, x10{}, rH1{}, x11{};

  auto LOAD = [&](int kt, f16x8& rH, f16x8& x1){
    int k0 = kt*32;
    rH = *(const f16x8*)&PgH[(long long)st_row*NN + k0 + 8*st_seg];
    if (xok) x1 = *(const f16x8*)&XC1[k0 + 8*xo];
  };
  auto STORE = [&](int buf, f16x8& rH, f16x8& x1){
    *(f16x8*)&sm.s1.PsH[buf][stw][st_row][8*(st_seg ^ a_sw)] = rH;
    if (xok) *(f16x8*)&sm.s1.XtH[buf][xc][8*xo] = x1;
  };
  f32x4 acc[5] = {};
  auto COMP = [&](int buf){
    f16x8 ah = *(const f16x8*)&sm.s1.PsH[buf][grp][ar][8*(lg ^ asw)];
    __builtin_amdgcn_s_setprio(1);
    #pragma unroll
    for (int cf = 0; cf < 5; ++cf) {
      int c = cf*16 + lr;
      f16x8 bh = *(const f16x8*)&sm.s1.XtH[buf][c][8*lg];
      acc[cf] = MFMA32(ah, bh, acc[cf]);
    }
    __builtin_amdgcn_s_setprio(0);
  };

  LOAD(0, rH0,x10);
  LOAD(1, rH1,x11);
  STORE(0, rH0,x10);
  barrier_lgkm();
  #pragma unroll
  for (int kt2 = 0; kt2 < 8; ++kt2) {
    int kt = kt2*2;
    if (kt+2 < 16) LOAD(kt+2, rH0,x10);
    COMP(0);
    STORE(1, rH1,x11);
    barrier_lgkm();
    if (kt+3 < 16) LOAD(kt+3, rH1,x11);
    COMP(1);
    if (kt+2 < 16) STORE(0, rH0,x10);
    barrier_lgkm();
  }

  // ---- dump g (split) into LDS union (staging dead after final barrier) ----
  {
    int go_ = grp*80;
    #pragma unroll
    for (int cf = 0; cf < 5; ++cf) {
      int col = go_ + cf*16 + lr;
      #pragma unroll
      for (int reg = 0; reg < 4; ++reg) {
        int row = w4*16 + lg*4 + reg;
        float v = acc[cf][reg];
        f16 hi = (f16)v;
        sm.s2.gH[row][col] = hi;
        sm.s2.gL[row][col] = (f16)(v - (float)hi);
      }
    }
  }
  barrier_lgkm();

  // ---- dense: K = [x(rm global, H) | g1(LDS split) | g2(LDS split)] ----
  constexpr int CFW = GATE ? 4 : 2;
  f32x4 accD[CFW] = {};
  const long long grow0 = bNN + rows0 + w4*16;
  const f16* xrH = XiRH + (grow0 + lr)*XS;
  #pragma unroll
  for (int c = 0; c < 15; ++c) {
    f16x4 a_h{}, a_l{};
    if (c < 5) {
      a_h = *(const f16x4*)&xrH[c*16 + 4*lg];
    } else {
      int gk = (c-5)*16 + 4*lg;
      a_h = *(const f16x4*)&sm.s2.gH[w4*16 + lr][gk];
      a_l = *(const f16x4*)&sm.s2.gL[w4*16 + lr][gk];
    }
    #pragma unroll
    for (int cf = 0; cf < CFW; ++cf) {
      int o = grp*(CFW*16) + cf*16 + lr;
      f16x4 b_h = *(const f16x4*)&WH[(long long)o*KD + c*16 + 4*lg];
      f16x4 b_l = *(const f16x4*)&WL[(long long)o*KD + c*16 + 4*lg];
      accD[cf] = MFMA16(a_h, b_h, accD[cf]);
      accD[cf] = MFMA16(a_h, b_l, accD[cf]);
      if (c >= 5) accD[cf] = MFMA16(a_l, b_h, accD[cf]);
    }
  }

  // ---- epilogue ----
  if constexpr (GATE) {
    #pragma unroll
    for (int cf = 0; cf < CFW; ++cf) {
      int o = grp*64 + cf*16 + lr;
      float bi = bias[o];
      #pragma unroll
      for (int reg = 0; reg < 4; ++reg) {
        long long grow = grow0 + lg*4 + reg;
        float v = 1.f/(1.f + expf(-(accD[cf][reg] + bi)));
        if (grp == 0) {
          float zh = v * hbuf[grow*HH + o];
          f16 hi = (f16)zh;
          XoRH[grow*XS + ns + o] = hi;
          XoCH[(long long)(ns+o)*RS + grow] = hi;
        } else {
          rb[grow*HH + (o - HH)] = v;
        }
      }
    }
    if (grp == 0 && lr < ns) {
      #pragma unroll
      for (int reg = 0; reg < 4; ++reg) {
        long long grow = grow0 + lg*4 + reg;
        f16 vh = XiRH[grow*XS + lr];
        XoRH[grow*XS + lr] = vh;
        XoCH[(long long)lr*RS + grow] = vh;
      }
    }
  } else {
    float gop[4] = {0.f,0.f,0.f,0.f};
    #pragma unroll
    for (int cf = 0; cf < CFW; ++cf) {
      int o = grp*32 + cf*16 + lr;
      float bi = bias[o];
      float pwv = 0.f;
      if constexpr (DEC) pwv = pWv[o];
      #pragma unroll
      for (int reg = 0; reg < 4; ++reg) {
        long long grow = grow0 + lg*4 + reg;
        float hc = tanhf(accD[cf][reg] + bi);
        float rv = rb[grow*HH + o];
        float hv = hbuf[grow*HH + o];
        float hn = rv*hv + (1.f - rv)*hc;
        hbuf[grow*HH + o] = hn;
        if (writeX) {
          f16 hi = (f16)hn;
          XoRH[grow*XS + ns_next + o] = hi;
          XoCH[(long long)(ns_next+o)*RS + grow] = hi;
        }
        if constexpr (DEC) gop[reg] += hn * pwv;
      }
    }
    if constexpr (DEC) {
      #pragma unroll
      for (int reg = 0; reg < 4; ++reg) {
        #pragma unroll
        for (int off = 8; off >= 1; off >>= 1)
          gop[reg] += __shfl_xor(gop[reg], off, 64);
      }
      if (grp == 1 && lr == 0) {
        #pragma unroll
        for (int reg = 0; reg < 4; ++reg)
          gpart[w4*16 + lg*4 + reg] = gop[reg];
      }
      barrier_lgkm();
      if (grp == 0 && lr == 0) {
        float pb0 = pbv[0];
        #pragma unroll
        for (int reg = 0; reg < 4; ++reg) {
          int n = rows0 + w4*16 + lg*4 + reg;
          long long grow = bNN + n;
          float go = gop[reg] + gpart[w4*16 + lg*4 + reg] + pb0;
          outp[((long long)b*TT + t)*NN + n] = go;
          if (writeX) {
            f16 hi = (f16)go;
            XoRH[grow*XS] = hi;
            XoCH[grow] = hi;
            float yv = s1src[(long long)b*TTNN + n];
            f16 hy = (f16)yv;
            XoRH[grow*XS + 1] = hy;
            XoCH[RS + grow] = hy;
          }
        }
      }
    } else {
      if (writeX && grp == 0 && lr == 0) {
        #pragma unroll
        for (int reg = 0; reg < 4; ++reg) {
          int n = rows0 + w4*16 + lg*4 + reg;
          long long grow = bNN + n;
          float v0 = s0src ? s0src[(long long)b*TTNN + n] : 0.f;
          f16 h0 = (f16)v0;
          XoRH[grow*XS] = h0;
          XoCH[grow] = h0;
          if (ns_next == 2 && s1src) {
            float v1 = s1src[(long long)b*TTNN + n];
            f16 h1 = (f16)v1;
            XoRH[grow*XS + 1] = h1;
            XoCH[RS + grow] = h1;
          }
        }
      }
    }
  }
}

// ---------------- E_dyn = ne + h @ hyper_W + hyper_b -----------------------------
__global__ __launch_bounds__(256) void edyn_k(
    const float* __restrict__ h, const float* __restrict__ ne,
    const float* __restrict__ hW, const float* __restrict__ hb, float* __restrict__ Ed)
{
  int row = blockIdx.x*4 + (threadIdx.x >> 6);
  int lane = threadIdx.x & 63;
  float hv = h[(long long)row*HH + lane];
  float myval = 0.f;
  #pragma unroll
  for (int e = 0; e < EE; ++e) {
    float v = hv * hW[lane*EE + e];
    #pragma unroll
    for (int off = 32; off >= 1; off >>= 1) v += __shfl_xor(v, off, 64);
    if (lane == e) myval = v;
  }
  if (lane < EE) {
    int n = row & 511;
    Ed[(long long)row*EE + lane] = ne[n*EE + lane] + hb[lane] + myval;
  }
}

extern "C" void kernel_launch(void* const* d_in, const int* in_sizes, int n_in,
                              void* d_out, int out_size, void* d_ws, size_t ws_size,
                              hipStream_t stream)
{
  const float* x    = (const float*)d_in[0];
  const float* ycov = (const float*)d_in[1];
  const float* ne   = (const float*)d_in[2];
  const float* egW  = (const float*)d_in[3];
  const float* egb  = (const float*)d_in[4];
  const float* euW  = (const float*)d_in[5];
  const float* eub  = (const float*)d_in[6];
  const float* dgW  = (const float*)d_in[7];
  const float* dgb  = (const float*)d_in[8];
  const float* duW  = (const float*)d_in[9];
  const float* dub  = (const float*)d_in[10];
  const float* pW   = (const float*)d_in[11];
  const float* pb   = (const float*)d_in[12];
  const float* hW   = (const float*)d_in[13];
  const float* hb   = (const float*)d_in[14];
  float* out = (float*)d_out;

  char* p = (char*)d_ws;
  f16* AsH  = (f16*)p; p += (size_t)NN*NN*2;
  f16* AsL  = (f16*)p; p += (size_t)NN*NN*2;
  f16* As2H = (f16*)p; p += (size_t)NN*NN*2;
  f16* AdH  = (f16*)p; p += (size_t)NB*NN*NN*2;
  f16* AdL  = (f16*)p; p += (size_t)NB*NN*NN*2;
  f16* Ad2H = (f16*)p; p += (size_t)NB*NN*NN*2;
  f16* XaRH = (f16*)p; p += (size_t)RS*XS*2;
  f16* XaCH = (f16*)p; p += (size_t)RS*XS*2;
  f16* XbRH = (f16*)p; p += (size_t)RS*XS*2;
  f16* XbCH = (f16*)p; p += (size_t)RS*XS*2;
  float* h  = (float*)p; p += (size_t)RS*HH*4;
  float* rb = (float*)p; p += (size_t)RS*HH*4;
  float* Ed = (float*)p; p += (size_t)RS*EE*4;
  f16* WgeH = (f16*)p; p += (size_t)128*KD*2;
  f16* WgeL = (f16*)p; p += (size_t)128*KD*2;
  f16* WueH = (f16*)p; p += (size_t)64*KD*2;
  f16* WueL = (f16*)p; p += (size_t)64*KD*2;
  f16* WgdH = (f16*)p; p += (size_t)128*KD*2;
  f16* WgdL = (f16*)p; p += (size_t)128*KD*2;
  f16* WudH = (f16*)p; p += (size_t)64*KD*2;
  f16* WudL = (f16*)p; p += (size_t)64*KD*2;

  fold_w_t<<<(128*KD+255)/256, 256, 0, stream>>>(egW, WgeH, WgeL, 65, 128);
  fold_w_t<<<(64*KD +255)/256, 256, 0, stream>>>(euW, WueH, WueL, 65, 64);
  fold_w_t<<<(128*KD+255)/256, 256, 0, stream>>>(dgW, WgdH, WgdL, 66, 128);
  fold_w_t<<<(64*KD +255)/256, 256, 0, stream>>>(duW, WudH, WudL, 66, 64);

  softmax_graph<<<64, 512, 0, stream>>>(ne, 0, AsH, AsL, 0);
  sq_mm<<<dim3(8,8,1), 256, 0, stream>>>(AsH, AsL, 0, As2H, 0);
  (void)hipMemsetAsync(h, 0, (size_t)RS*HH*4, stream);
  (void)hipMemsetAsync(XaRH, 0, (size_t)RS*XS*2*4, stream);  // all 4 X arrays contiguous
  fill_col<<<(RS+255)/256, 256, 0, stream>>>(XaRH, XaCH, 0, x, (long long)TTNN);

  dim3 fgrid(NB, 8);
  for (int t = 0; t < TT; ++t) {
    fused_half<1,0><<<fgrid, 512, 0, stream>>>(
        AsH, As2H, 0,
        XaRH, XaCH, XbRH, XbCH,
        WgeH, WgeL, egb, h, rb, nullptr, nullptr, nullptr, t,
        nullptr, nullptr, 1, 0, 1);
    fused_half<0,0><<<fgrid, 512, 0, stream>>>(
        AsH, As2H, 0,
        XbRH, XbCH, XaRH, XaCH,
        WueH, WueL, eub, h, rb, nullptr, nullptr, nullptr, t,
        (t < TT-1 ? x + (size_t)(t+1)*NN : nullptr),
        (t < TT-1 ? nullptr : ycov),
        1, (t < TT-1 ? 1 : 2), 1);
  }

  edyn_k<<<RS/4, 256, 0, stream>>>(h, ne, hW, hb, Ed);
  softmax_graph<<<NB*64, 512, 0, stream>>>(Ed, (long long)NN*EE, AdH, AdL, (long long)NN*NN);
  sq_mm<<<dim3(8,8,NB), 256, 0, stream>>>(AdH, AdL, (long long)NN*NN, Ad2H, (long long)NN*NN);

  for (int t = 0; t < TT; ++t) {
    fused_half<1,0><<<fgrid, 512, 0, stream>>>(
        AdH, Ad2H, (long long)NN*NN,
        XaRH, XaCH, XbRH, XbCH,
        WgdH, WgdL, dgb, h, rb, nullptr, nullptr, nullptr, t,
        nullptr, nullptr, 2, 0, 1);
    fused_half<0,1><<<fgrid, 512, 0, stream>>>(
        AdH, Ad2H, (long long)NN*NN,
        XbRH, XbCH, XaRH, XaCH,
        WudH, WudL, dub, h, rb, pW, pb, out, t,
        nullptr, (t < TT-1 ? ycov + (size_t)(t+1)*NN : nullptr),
        2, 2, (t < TT-1 ? 1 : 0));
  }
}

// Round 20
// 1022.534 us; speedup vs baseline: 3.2580x; 1.2637x over previous
//
#include <hip/hip_runtime.h>

#define NB 32
#define TT 12
#define NN 512
#define HH 64
#define EE 10
#define XS 80       // X row width (halves)
#define KD 240      // dense K = 3*80
#define RS (NB*NN)  // 16384 global rows
#define TTNN (TT*NN)
#define GP 164

typedef _Float16 f16;
typedef __attribute__((ext_vector_type(4))) _Float16 f16x4;
typedef __attribute__((ext_vector_type(8))) _Float16 f16x8;
typedef __attribute__((ext_vector_type(4))) float f32x4;

#define MFMA32(a,bb,c) __builtin_amdgcn_mfma_f32_16x16x32_f16(a,bb,c,0,0,0)
#define MFMA16(a,bb,c) __builtin_amdgcn_mfma_f32_16x16x16f16(a,bb,c,0,0,0)

__device__ __forceinline__ void barrier_lgkm() {
  asm volatile("s_waitcnt lgkmcnt(0)" ::: "memory");
  __builtin_amdgcn_s_barrier();
  __builtin_amdgcn_sched_barrier(0);
}

union SMem {
  struct {
    f16 PsH[2][2][64][32];        // [buf][A=0/A2=1][row][k]  16 KB
    f16 XtH[2][80][40];           // [buf][col][k]            12.8 KB
  } s1;
  struct {
    f16 gH[64][GP];               // [row][g1|g2]             21 KB
  } s2;
};

// ---------------- fold Chebyshev into weights; transpose to [O][KD]; f16 --------
__global__ void fold_w_t(const float* __restrict__ src, f16* __restrict__ WtH,
                         int C, int O){
  int idx = blockIdx.x*256 + threadIdx.x;
  if (idx >= O*KD) return;
  int o = idx / KD;
  int k = idx % KD;
  int s = k / XS, c = k % XS;
  float v = 0.f;
  if (c < C) {
    if (s == 0)      v = src[c*O+o] - src[(2*C+c)*O+o];
    else if (s == 1) v = src[(C+c)*O+o];
    else             v = 2.f*src[(2*C+c)*O+o];
  }
  WtH[idx] = (f16)v;
}

// ---------------- A = softmax(relu(E E^T)): 8 rows/block, wave-per-row ----------
__global__ __launch_bounds__(512) void softmax_graph(
    const float* __restrict__ Emb, long long ebs,
    f16* __restrict__ AH, long long abs_)
{
  __shared__ float Es[NN*EE];
  int b  = blockIdx.x >> 6;
  int rt = blockIdx.x & 63;
  const float* Eb = Emb + (long long)b*ebs;
  int tid = threadIdx.x;
  for (int i = tid; i < NN*EE; i += 512) Es[i] = Eb[i];
  __syncthreads();
  int wave = tid >> 6, lane = tid & 63;
  int r = rt*8 + wave;
  float q[EE];
  #pragma unroll
  for (int e = 0; e < EE; ++e) q[e] = Es[r*EE + e];
  float sv[8];
  float mx = 0.f;
  #pragma unroll
  for (int j = 0; j < 8; ++j) {
    int m = 64*j + lane;
    float s = 0.f;
    #pragma unroll
    for (int e = 0; e < EE; ++e) s += q[e]*Es[m*EE + e];
    s = fmaxf(s, 0.f);
    sv[j] = s;
    mx = fmaxf(mx, s);
  }
  #pragma unroll
  for (int off = 32; off >= 1; off >>= 1) mx = fmaxf(mx, __shfl_xor(mx, off, 64));
  float sm = 0.f;
  #pragma unroll
  for (int j = 0; j < 8; ++j) { sv[j] = expf(sv[j] - mx); sm += sv[j]; }
  #pragma unroll
  for (int off = 32; off >= 1; off >>= 1) sm += __shfl_xor(sm, off, 64);
  float inv = 1.f / sm;
  #pragma unroll
  for (int j = 0; j < 8; ++j) {
    int m = 64*j + lane;
    AH[(long long)b*abs_ + (long long)r*NN + m] = (f16)(sv[j] * inv);
  }
}

// ---------------- B = A @ A, single-f16 ------------------------------------------
__global__ __launch_bounds__(256) void sq_mm(
    const f16* __restrict__ AH, long long astr,
    f16* __restrict__ BH, long long bstr)
{
  __shared__ f16 RsH[64][36], CsH[64][34];
  int b = blockIdx.z;
  int rows0 = blockIdx.y*64, cols0 = blockIdx.x*64;
  const f16* Ah = AH + (long long)b*astr;
  int tid = threadIdx.x, l = tid & 63, w = tid >> 6, lr = l & 15, lg = l >> 4;
  int ar = w*16 + lr;
  int st_row = tid >> 2, st_seg = tid & 3;
  int sx_m = tid >> 3, sx_sub = tid & 7;
  f32x4 acc[4] = {};
  for (int kt = 0; kt < 16; ++kt) {
    int k0 = kt*32;
    barrier_lgkm();
    {
      f16x8 vh = *(const f16x8*)&Ah[(long long)(rows0+st_row)*NN + k0 + 8*st_seg];
      *(f16x8*)&RsH[st_row][8*st_seg] = vh;
    }
    #pragma unroll
    for (int j = 0; j < 2; ++j) {
      int c4 = sx_sub + 8*j;   // 0..15
      f16x4 vh = *(const f16x4*)&Ah[(long long)(k0+sx_m)*NN + cols0 + 4*c4];
      #pragma unroll
      for (int q = 0; q < 4; ++q)
        CsH[4*c4+q][sx_m] = vh[q];
    }
    barrier_lgkm();
    f16x8 a_h = *(const f16x8*)&RsH[ar][8*lg];
    #pragma unroll
    for (int cf = 0; cf < 4; ++cf) {
      int c = cf*16 + lr;
      f16x8 b_h = *(const f16x8*)&CsH[c][8*lg];
      acc[cf] = MFMA32(a_h, b_h, acc[cf]);
    }
  }
  #pragma unroll
  for (int cf = 0; cf < 4; ++cf) {
    #pragma unroll
    for (int reg = 0; reg < 4; ++reg) {
      int r = rows0 + w*16 + lg*4 + reg;
      int c = cols0 + cf*16 + lr;
      BH[(long long)b*bstr + (long long)r*NN + c] = (f16)acc[cf][reg];
    }
  }
}

// ---------------- write one special column of X (dual layout, single f16) --------
__global__ void fill_col(f16* __restrict__ XRH, f16* __restrict__ XCH, int col,
                         const float* __restrict__ src, long long sstr){
  int row = blockIdx.x*256 + threadIdx.x;
  if (row >= RS) return;
  float v = src[(long long)(row>>9)*sstr + (row & 511)];
  f16 hi = (f16)v;
  XRH[(long long)row*XS + col] = hi;
  XCH[(long long)col*RS + row] = hi;
}

// ---------------- fused half-step: single-f16 everywhere -------------------------
template<int GATE, int DEC>
__global__ __launch_bounds__(512, 2) void fused_half(
    const f16* __restrict__ AH, const f16* __restrict__ A2H, long long astr,
    const f16* __restrict__ XiRH, const f16* __restrict__ XiCH,
    f16* __restrict__ XoRH, f16* __restrict__ XoCH,
    const f16* __restrict__ WH,
    const float* __restrict__ bias,
    float* __restrict__ hbuf, float* __restrict__ rb,
    const float* __restrict__ pWv, const float* __restrict__ pbv,
    float* __restrict__ outp, int t,
    const float* __restrict__ s0src, const float* __restrict__ s1src,
    int ns, int ns_next, int writeX)
{
  __shared__ SMem sm;
  __shared__ float gpart[64];
  const int b = blockIdx.x;
  const int rows0 = blockIdx.y * 64;
  const long long bNN = (long long)b*NN;
  const int tid = threadIdx.x;
  const int w = tid >> 6, l = tid & 63;
  const int lr = l & 15, lg = l >> 4;
  const int grp = w >> 2;
  const int w4 = w & 3;
  const int ar = w4*16 + lr;
  const int asw = (ar >> 2) & 3;

  // A/A2 staging mapping: tid<256 stages A-H, tid>=256 stages A2-H
  const int stw = (tid < 256) ? 0 : 1;
  const int at = tid & 255;
  const int st_row = at >> 2, st_seg = at & 3;
  const int a_sw = (st_row >> 2) & 3;
  const f16* PgH = (stw ? A2H : AH) + (long long)b*astr + (long long)rows0*NN;

  // X staging (col-major source, H only): tid<320 covers 80 cols x 4 chunks
  const int xc = tid >> 2;         // 0..127 (valid < 80)
  const int xo = tid & 3;
  const int xok = (xc < 80);
  const f16* XC1 = XiCH + (long long)(xok ? xc : 0)*RS + bNN;

  f16x8 rH0{}, x10{}, rH1{}, x11{};

  auto LOAD = [&](int kt, f16x8& rH, f16x8& x1){
    int k0 = kt*32;
    rH = *(const f16x8*)&PgH[(long long)st_row*NN + k0 + 8*st_seg];
    if (xok) x1 = *(const f16x8*)&XC1[k0 + 8*xo];
  };
  auto STORE = [&](int buf, f16x8& rH, f16x8& x1){
    *(f16x8*)&sm.s1.PsH[buf][stw][st_row][8*(st_seg ^ a_sw)] = rH;
    if (xok) *(f16x8*)&sm.s1.XtH[buf][xc][8*xo] = x1;
  };
  f32x4 acc[5] = {};
  auto COMP = [&](int buf){
    f16x8 ah = *(const f16x8*)&sm.s1.PsH[buf][grp][ar][8*(lg ^ asw)];
    __builtin_amdgcn_s_setprio(1);
    #pragma unroll
    for (int cf = 0; cf < 5; ++cf) {
      int c = cf*16 + lr;
      f16x8 bh = *(const f16x8*)&sm.s1.XtH[buf][c][8*lg];
      acc[cf] = MFMA32(ah, bh, acc[cf]);
    }
    __builtin_amdgcn_s_setprio(0);
  };

  LOAD(0, rH0,x10);
  LOAD(1, rH1,x11);
  STORE(0, rH0,x10);
  barrier_lgkm();
  #pragma unroll
  for (int kt2 = 0; kt2 < 8; ++kt2) {
    int kt = kt2*2;
    if (kt+2 < 16) LOAD(kt+2, rH0,x10);
    COMP(0);
    STORE(1, rH1,x11);
    barrier_lgkm();
    if (kt+3 < 16) LOAD(kt+3, rH1,x11);
    COMP(1);
    if (kt+2 < 16) STORE(0, rH0,x10);
    barrier_lgkm();
  }

  // ---- dump g (single f16) into LDS union ----
  {
    int go_ = grp*80;
    #pragma unroll
    for (int cf = 0; cf < 5; ++cf) {
      int col = go_ + cf*16 + lr;
      #pragma unroll
      for (int reg = 0; reg < 4; ++reg) {
        int row = w4*16 + lg*4 + reg;
        sm.s2.gH[row][col] = (f16)acc[cf][reg];
      }
    }
  }
  barrier_lgkm();

  // ---- dense: K = [x(rm global, H) | g1(LDS) | g2(LDS)], W single f16 ----
  constexpr int CFW = GATE ? 4 : 2;
  f32x4 accD[CFW] = {};
  const long long grow0 = bNN + rows0 + w4*16;
  const f16* xrH = XiRH + (grow0 + lr)*XS;
  #pragma unroll
  for (int c = 0; c < 15; ++c) {
    f16x4 a_h;
    if (c < 5) {
      a_h = *(const f16x4*)&xrH[c*16 + 4*lg];
    } else {
      a_h = *(const f16x4*)&sm.s2.gH[w4*16 + lr][(c-5)*16 + 4*lg];
    }
    #pragma unroll
    for (int cf = 0; cf < CFW; ++cf) {
      int o = grp*(CFW*16) + cf*16 + lr;
      f16x4 b_h = *(const f16x4*)&WH[(long long)o*KD + c*16 + 4*lg];
      accD[cf] = MFMA16(a_h, b_h, accD[cf]);
    }
  }

  // ---- epilogue ----
  if constexpr (GATE) {
    #pragma unroll
    for (int cf = 0; cf < CFW; ++cf) {
      int o = grp*64 + cf*16 + lr;
      float bi = bias[o];
      #pragma unroll
      for (int reg = 0; reg < 4; ++reg) {
        long long grow = grow0 + lg*4 + reg;
        float v = 1.f/(1.f + expf(-(accD[cf][reg] + bi)));
        if (grp == 0) {
          float zh = v * hbuf[grow*HH + o];
          f16 hi = (f16)zh;
          XoRH[grow*XS + ns + o] = hi;
          XoCH[(long long)(ns+o)*RS + grow] = hi;
        } else {
          rb[grow*HH + (o - HH)] = v;
        }
      }
    }
    if (grp == 0 && lr < ns) {
      #pragma unroll
      for (int reg = 0; reg < 4; ++reg) {
        long long grow = grow0 + lg*4 + reg;
        f16 vh = XiRH[grow*XS + lr];
        XoRH[grow*XS + lr] = vh;
        XoCH[(long long)lr*RS + grow] = vh;
      }
    }
  } else {
    float gop[4] = {0.f,0.f,0.f,0.f};
    #pragma unroll
    for (int cf = 0; cf < CFW; ++cf) {
      int o = grp*32 + cf*16 + lr;
      float bi = bias[o];
      float pwv = 0.f;
      if constexpr (DEC) pwv = pWv[o];
      #pragma unroll
      for (int reg = 0; reg < 4; ++reg) {
        long long grow = grow0 + lg*4 + reg;
        float hc = tanhf(accD[cf][reg] + bi);
        float rv = rb[grow*HH + o];
        float hv = hbuf[grow*HH + o];
        float hn = rv*hv + (1.f - rv)*hc;
        hbuf[grow*HH + o] = hn;
        if (writeX) {
          f16 hi = (f16)hn;
          XoRH[grow*XS + ns_next + o] = hi;
          XoCH[(long long)(ns_next+o)*RS + grow] = hi;
        }
        if constexpr (DEC) gop[reg] += hn * pwv;
      }
    }
    if constexpr (DEC) {
      #pragma unroll
      for (int reg = 0; reg < 4; ++reg) {
        #pragma unroll
        for (int off = 8; off >= 1; off >>= 1)
          gop[reg] += __shfl_xor(gop[reg], off, 64);
      }
      if (grp == 1 && lr == 0) {
        #pragma unroll
        for (int reg = 0; reg < 4; ++reg)
          gpart[w4*16 + lg*4 + reg] = gop[reg];
      }
      barrier_lgkm();
      if (grp == 0 && lr == 0) {
        float pb0 = pbv[0];
        #pragma unroll
        for (int reg = 0; reg < 4; ++reg) {
          int n = rows0 + w4*16 + lg*4 + reg;
          long long grow = bNN + n;
          float go = gop[reg] + gpart[w4*16 + lg*4 + reg] + pb0;
          outp[((long long)b*TT + t)*NN + n] = go;
          if (writeX) {
            f16 hi = (f16)go;
            XoRH[grow*XS] = hi;
            XoCH[grow] = hi;
            float yv = s1src[(long long)b*TTNN + n];
            f16 hy = (f16)yv;
            XoRH[grow*XS + 1] = hy;
            XoCH[RS + grow] = hy;
          }
        }
      }
    } else {
      if (writeX && grp == 0 && lr == 0) {
        #pragma unroll
        for (int reg = 0; reg < 4; ++reg) {
          int n = rows0 + w4*16 + lg*4 + reg;
          long long grow = bNN + n;
          float v0 = s0src ? s0src[(long long)b*TTNN + n] : 0.f;
          f16 h0 = (f16)v0;
          XoRH[grow*XS] = h0;
          XoCH[grow] = h0;
          if (ns_next == 2 && s1src) {
            float v1 = s1src[(long long)b*TTNN + n];
            f16 h1 = (f16)v1;
            XoRH[grow*XS + 1] = h1;
            XoCH[RS + grow] = h1;
          }
        }
      }
    }
  }
}

// ---------------- E_dyn = ne + h @ hyper_W + hyper_b -----------------------------
__global__ __launch_bounds__(256) void edyn_k(
    const float* __restrict__ h, const float* __restrict__ ne,
    const float* __restrict__ hW, const float* __restrict__ hb, float* __restrict__ Ed)
{
  int row = blockIdx.x*4 + (threadIdx.x >> 6);
  int lane = threadIdx.x & 63;
  float hv = h[(long long)row*HH + lane];
  float myval = 0.f;
  #pragma unroll
  for (int e = 0; e < EE; ++e) {
    float v = hv * hW[lane*EE + e];
    #pragma unroll
    for (int off = 32; off >= 1; off >>= 1) v += __shfl_xor(v, off, 64);
    if (lane == e) myval = v;
  }
  if (lane < EE) {
    int n = row & 511;
    Ed[(long long)row*EE + lane] = ne[n*EE + lane] + hb[lane] + myval;
  }
}

extern "C" void kernel_launch(void* const* d_in, const int* in_sizes, int n_in,
                              void* d_out, int out_size, void* d_ws, size_t ws_size,
                              hipStream_t stream)
{
  const float* x    = (const float*)d_in[0];
  const float* ycov = (const float*)d_in[1];
  const float* ne   = (const float*)d_in[2];
  const float* egW  = (const float*)d_in[3];
  const float* egb  = (const float*)d_in[4];
  const float* euW  = (const float*)d_in[5];
  const float* eub  = (const float*)d_in[6];
  const float* dgW  = (const float*)d_in[7];
  const float* dgb  = (const float*)d_in[8];
  const float* duW  = (const float*)d_in[9];
  const float* dub  = (const float*)d_in[10];
  const float* pW   = (const float*)d_in[11];
  const float* pb   = (const float*)d_in[12];
  const float* hW   = (const float*)d_in[13];
  const float* hb   = (const float*)d_in[14];
  float* out = (float*)d_out;

  char* p = (char*)d_ws;
  f16* AsH  = (f16*)p; p += (size_t)NN*NN*2;
  f16* As2H = (f16*)p; p += (size_t)NN*NN*2;
  f16* AdH  = (f16*)p; p += (size_t)NB*NN*NN*2;
  f16* Ad2H = (f16*)p; p += (size_t)NB*NN*NN*2;
  f16* XaRH = (f16*)p; p += (size_t)RS*XS*2;
  f16* XaCH = (f16*)p; p += (size_t)RS*XS*2;
  f16* XbRH = (f16*)p; p += (size_t)RS*XS*2;
  f16* XbCH = (f16*)p; p += (size_t)RS*XS*2;
  float* h  = (float*)p; p += (size_t)RS*HH*4;
  float* rb = (float*)p; p += (size_t)RS*HH*4;
  float* Ed = (float*)p; p += (size_t)RS*EE*4;
  f16* WgeH = (f16*)p; p += (size_t)128*KD*2;
  f16* WueH = (f16*)p; p += (size_t)64*KD*2;
  f16* WgdH = (f16*)p; p += (size_t)128*KD*2;
  f16* WudH = (f16*)p; p += (size_t)64*KD*2;

  fold_w_t<<<(128*KD+255)/256, 256, 0, stream>>>(egW, WgeH, 65, 128);
  fold_w_t<<<(64*KD +255)/256, 256, 0, stream>>>(euW, WueH, 65, 64);
  fold_w_t<<<(128*KD+255)/256, 256, 0, stream>>>(dgW, WgdH, 66, 128);
  fold_w_t<<<(64*KD +255)/256, 256, 0, stream>>>(duW, WudH, 66, 64);

  softmax_graph<<<64, 512, 0, stream>>>(ne, 0, AsH, 0);
  sq_mm<<<dim3(8,8,1), 256, 0, stream>>>(AsH, 0, As2H, 0);
  (void)hipMemsetAsync(h, 0, (size_t)RS*HH*4, stream);
  (void)hipMemsetAsync(XaRH, 0, (size_t)RS*XS*2*4, stream);  // all 4 X arrays contiguous
  fill_col<<<(RS+255)/256, 256, 0, stream>>>(XaRH, XaCH, 0, x, (long long)TTNN);

  dim3 fgrid(NB, 8);
  for (int t = 0; t < TT; ++t) {
    fused_half<1,0><<<fgrid, 512, 0, stream>>>(
        AsH, As2H, 0,
        XaRH, XaCH, XbRH, XbCH,
        WgeH, egb, h, rb, nullptr, nullptr, nullptr, t,
        nullptr, nullptr, 1, 0, 1);
    fused_half<0,0><<<fgrid, 512, 0, stream>>>(
        AsH, As2H, 0,
        XbRH, XbCH, XaRH, XaCH,
        WueH, eub, h, rb, nullptr, nullptr, nullptr, t,
        (t < TT-1 ? x + (size_t)(t+1)*NN : nullptr),
        (t < TT-1 ? nullptr : ycov),
        1, (t < TT-1 ? 1 : 2), 1);
  }

  edyn_k<<<RS/4, 256, 0, stream>>>(h, ne, hW, hb, Ed);
  softmax_graph<<<NB*64, 512, 0, stream>>>(Ed, (long long)NN*EE, AdH, (long long)NN*NN);
  sq_mm<<<dim3(8,8,NB), 256, 0, stream>>>(AdH, (long long)NN*NN, Ad2H, (long long)NN*NN);

  for (int t = 0; t < TT; ++t) {
    fused_half<1,0><<<fgrid, 512, 0, stream>>>(
        AdH, Ad2H, (long long)NN*NN,
        XaRH, XaCH, XbRH, XbCH,
        WgdH, dgb, h, rb, nullptr, nullptr, nullptr, t,
        nullptr, nullptr, 2, 0, 1);
    fused_half<0,1><<<fgrid, 512, 0, stream>>>(
        AdH, Ad2H, (long long)NN*NN,
        XbRH, XbCH, XaRH, XaCH,
        WudH, dub, h, rb, pW, pb, out, t,
        nullptr, (t < TT-1 ? ycov + (size_t)(t+1)*NN : nullptr),
        2, 2, (t < TT-1 ? 1 : 0));
  }
}